// Round 10
// baseline (4324.205 us; speedup 1.0000x reference)
//
#include <hip/hip_runtime.h>

#define F_IN 512
#define HID 128
#define KHOPS 10
#define COUT 10

typedef unsigned int uint;
typedef unsigned short ushort;
typedef float f32x4 __attribute__((ext_vector_type(4)));
typedef short bf16x8 __attribute__((ext_vector_type(8)));

__device__ __forceinline__ uint f2bf1(float f) {
    uint u = __float_as_uint(f);
    return (u + 0x7fffu + ((u >> 16) & 1u)) >> 16;   // RNE
}
__device__ __forceinline__ uint packbf(float a, float b) {
    return f2bf1(a) | (f2bf1(b) << 16);
}
__device__ __forceinline__ float bflo(uint u) { return __uint_as_float(u << 16); }
__device__ __forceinline__ float bfhi(uint u) { return __uint_as_float(u & 0xffff0000u); }
__device__ __forceinline__ int pad16i(int c) { return (c + 15) & ~15; }

// ---------------- W_in -> bf16, pre-swizzled into MFMA B-fragment lane order ----------------
__global__ __launch_bounds__(256) void wprep_kernel(
    const float* __restrict__ Win, ushort* __restrict__ Wsw)
{
    const int t = blockIdx.x * blockDim.x + threadIdx.x;
    if (t >= 2 * 16 * 8 * 64) return;
    const int l = t & 63;
    const int c = (t >> 6) & 7;
    const int s = (t >> 9) & 15;
    const int br = t >> 13;
    const int col = c * 16 + (l & 15);
    const int k0 = s * 32 + (l >> 4) * 8;
    const float* W = Win + (size_t)br * F_IN * HID;
    uint o0 = packbf(W[(size_t)(k0 + 0) * HID + col], W[(size_t)(k0 + 1) * HID + col]);
    uint o1 = packbf(W[(size_t)(k0 + 2) * HID + col], W[(size_t)(k0 + 3) * HID + col]);
    uint o2 = packbf(W[(size_t)(k0 + 4) * HID + col], W[(size_t)(k0 + 5) * HID + col]);
    uint o3 = packbf(W[(size_t)(k0 + 6) * HID + col], W[(size_t)(k0 + 7) * HID + col]);
    *(uint4*)(Wsw + (size_t)t * 8) = make_uint4(o0, o1, o2, o3);
}

// ---------------- GEMM via MFMA: h = bf16(x @ W + b) ----------------
__global__ __launch_bounds__(256) void gemm_mfma_kernel(
    const float* __restrict__ x, const ushort* __restrict__ Wsw,
    const float* __restrict__ bin, uint* __restrict__ h1, uint* __restrict__ h2, int n)
{
    const int br = blockIdx.y;
    const uint4* Wb = (const uint4*)(Wsw + (size_t)br * 16 * 8 * 64 * 8);
    const float* bias = bin + br * HID;
    uint* h = br ? h2 : h1;

    const int w = threadIdx.x >> 6;
    const int lane = threadIdx.x & 63;
    const int r16 = lane & 15;
    const int kg = lane >> 4;

    const int rowbase = blockIdx.x * 128 + w * 32;

    f32x4 acc[2][8];
#pragma unroll
    for (int f = 0; f < 2; ++f)
#pragma unroll
        for (int c = 0; c < 8; ++c) acc[f][c] = (f32x4)0.f;

    int rA0 = rowbase + r16;      if (rA0 > n - 1) rA0 = n - 1;
    int rA1 = rowbase + 16 + r16; if (rA1 > n - 1) rA1 = n - 1;
    const float* xp0 = x + (size_t)rA0 * F_IN + kg * 8;
    const float* xp1 = x + (size_t)rA1 * F_IN + kg * 8;

    for (int s = 0; s < 16; ++s) {
        const float4 a0lo = *(const float4*)(xp0 + s * 32);
        const float4 a0hi = *(const float4*)(xp0 + s * 32 + 4);
        const float4 a1lo = *(const float4*)(xp1 + s * 32);
        const float4 a1hi = *(const float4*)(xp1 + s * 32 + 4);
        union { uint4 u; bf16x8 v; } af0, af1;
        af0.u = make_uint4(packbf(a0lo.x, a0lo.y), packbf(a0lo.z, a0lo.w),
                           packbf(a0hi.x, a0hi.y), packbf(a0hi.z, a0hi.w));
        af1.u = make_uint4(packbf(a1lo.x, a1lo.y), packbf(a1lo.z, a1lo.w),
                           packbf(a1hi.x, a1hi.y), packbf(a1hi.z, a1hi.w));
        const uint4* wq = Wb + (size_t)(s * 8) * 64 + lane;
#pragma unroll
        for (int c = 0; c < 8; ++c) {
            union { uint4 u; bf16x8 v; } bfr;
            bfr.u = wq[c * 64];
            acc[0][c] = __builtin_amdgcn_mfma_f32_16x16x32_bf16(af0.v, bfr.v, acc[0][c], 0, 0, 0);
            acc[1][c] = __builtin_amdgcn_mfma_f32_16x16x32_bf16(af1.v, bfr.v, acc[1][c], 0, 0, 0);
        }
    }

    float bv[8];
#pragma unroll
    for (int c = 0; c < 8; ++c) bv[c] = bias[c * 16 + r16];

#pragma unroll
    for (int f = 0; f < 2; ++f)
#pragma unroll
        for (int c = 0; c < 8; ++c)
#pragma unroll
            for (int i = 0; i < 4; ++i) {
                const float v = acc[f][c][i] + bv[c];
                const float o = __shfl_xor(v, 1);
                const int row = rowbase + f * 16 + kg * 4 + i;
                if (!(lane & 1) && row < n)
                    h[(size_t)row * 64 + c * 8 + (r16 >> 1)] = packbf(v, o);
            }
}

// ---------------- CSR build (padded-to-16 rows) ----------------
// temp record: lo = (col << 8) | rowlocal, hi = w bits
// final cw record: lo = col*256 byte offset, hi = w bits; rows padded to x16 with (0,0)

__global__ void bhist2_kernel(const int* __restrict__ r1, int E1,
                              const int* __restrict__ r2, int E2,
                              int* __restrict__ rcnt, int n)
{
    const int br = blockIdx.y;
    const int* rows = br ? r2 : r1;
    const int E = br ? E2 : E1;
    int* rc = rcnt + (size_t)br * n;
    for (int i = blockIdx.x * blockDim.x + threadIdx.x; i < E; i += gridDim.x * blockDim.x)
        atomicAdd(&rc[rows[i]], 1);
}

// single block per branch: padded row scan + unpadded bucket scan
#define SCAN_CHUNK 448   // multiple of 64, 256*448 >= n
__global__ __launch_bounds__(256) void scan2_kernel(
    const int* __restrict__ rcnt, int* __restrict__ rowp1, int* __restrict__ rowp2,
    int* __restrict__ bbase, int* __restrict__ bcur,
    int n, int nb, int E1, int E2)
{
    __shared__ int spad[256], sunp[256];
    const int br = blockIdx.y;
    const int* rc = rcnt + (size_t)br * n;
    int* rowp = br ? rowp2 : rowp1;
    int* bb = bbase + (size_t)br * (nb + 1);
    int* cur = bcur + (size_t)br * nb;
    const int E = br ? E2 : E1;
    const int t = threadIdx.x;
    const int start = t * SCAN_CHUNK;
    const int end = (start + SCAN_CHUNK < n) ? start + SCAN_CHUNK : n;
    int sp = 0, su = 0;
    for (int i = start; i < end; ++i) { int c = rc[i]; sp += pad16i(c); su += c; }
    spad[t] = sp; sunp[t] = su;
    __syncthreads();
    if (t == 0) {
        int rp = 0, up = 0;
        for (int i = 0; i < 256; ++i) {
            int a = spad[i], b = sunp[i];
            spad[i] = rp; sunp[i] = up;
            rp += a; up += b;
        }
        rowp[n] = rp;       // padded total
        bb[nb] = E;
    }
    __syncthreads();
    int rp = spad[t];
    for (int i = start; i < end; ++i) { rowp[i] = rp; rp += pad16i(rc[i]); }
    // buckets are aligned to thread chunks (SCAN_CHUNK % 64 == 0)
    int up = sunp[t];
    for (int b = start >> 6; b < (end + 63) >> 6; ++b) {
        bb[b] = up; cur[b] = up;
        const int rend = (b * 64 + 64 < n) ? b * 64 + 64 : n;
        for (int r = b * 64; r < rend; ++r) up += rc[r];
    }
}

#define SCAT_BLOCKS 256
__global__ __launch_bounds__(256) void bscat_kernel(
    const int* __restrict__ r1, const int* __restrict__ c1, const float* __restrict__ w1, int E1,
    const int* __restrict__ r2, const int* __restrict__ c2, const float* __restrict__ w2, int E2,
    int* __restrict__ bcur, int2* __restrict__ t1, int2* __restrict__ t2, int nb)
{
    extern __shared__ int sh[];
    int* lh = sh;
    int* lbase = sh + nb;
    const int br = blockIdx.y;
    const int* rows = br ? r2 : r1;
    const int* cols = br ? c2 : c1;
    const float* w  = br ? w2 : w1;
    const int E = br ? E2 : E1;
    int* cur = bcur + (size_t)br * nb;
    int2* tcw = br ? t2 : t1;
    const int t = threadIdx.x;

    for (int i = t; i < nb; i += 256) lh[i] = 0;
    __syncthreads();

    const int per = (E + SCAT_BLOCKS - 1) / SCAT_BLOCKS;
    const int c0 = blockIdx.x * per;
    const int cend = (c0 + per < E) ? c0 + per : E;

    for (int i = c0 + t; i < cend; i += 256)
        atomicAdd(&lh[rows[i] >> 6], 1);
    __syncthreads();
    for (int b = t; b < nb; b += 256) {
        int c = lh[b];
        lbase[b] = c ? atomicAdd(&cur[b], c) : 0;
        lh[b] = 0;
    }
    __syncthreads();
    for (int i = c0 + t; i < cend; i += 256) {
        int r = rows[i];
        int b = r >> 6;
        int p = atomicAdd(&lh[b], 1);
        uint lo = ((uint)cols[i] << 8) | (uint)(r & 63);
        tcw[lbase[b] + p] = make_int2((int)lo, __float_as_int(w[i]));
    }
}

// counting place into padded final positions + zero-fill pads
__global__ __launch_bounds__(256) void bsort_kernel(
    const int* __restrict__ bbase,
    const int2* __restrict__ t1, const int2* __restrict__ t2,
    const int* __restrict__ rowp1, const int* __restrict__ rowp2,
    int2* __restrict__ cw1, int2* __restrict__ cw2, int nb, int n)
{
    __shared__ int pos[64];
    const int br = blockIdx.y;
    const int* bb = bbase + (size_t)br * (nb + 1);
    const int2* tcw = br ? t2 : t1;
    const int* rowp = br ? rowp2 : rowp1;
    int2* cw = br ? cw2 : cw1;
    const int b = blockIdx.x;
    const int t = threadIdx.x;
    const int base = bb[b];
    const int m = bb[b + 1] - base;
    if (t < 64) {
        const int g = b * 64 + t;
        pos[t] = (g < n) ? rowp[g] : 0;
    }
    __syncthreads();
    for (int i = t; i < m; i += 256) {
        int2 e = tcw[base + i];
        int r = (uint)e.x & 63;
        int p = atomicAdd(&pos[r], 1);
        cw[p] = make_int2((int)((uint)e.x & 0xFFFFFF00u), e.y);
    }
    __syncthreads();
    if (t < 64) {
        const int g = b * 64 + t;
        if (g < n) {
            const int pend = rowp[g + 1];
            for (int p = pos[t]; p < pend; ++p) cw[p] = make_int2(0, 0);  // pad edges
        }
    }
}

// ---------------- SpMM quad-gather, padded rows, 2 rows/wave + fused z2 ----------------
struct BrArgs {
    const int* rowp;
    const int2* cw;
    const uint* hin;
    uint* hout;
    const float* Wo;
};

#define FMA8(a, gv, q)                                                   \
    a[0] = fmaf(q, bflo(gv.x), a[0]); a[1] = fmaf(q, bfhi(gv.x), a[1]);  \
    a[2] = fmaf(q, bflo(gv.y), a[2]); a[3] = fmaf(q, bfhi(gv.y), a[3]);  \
    a[4] = fmaf(q, bflo(gv.z), a[4]); a[5] = fmaf(q, bfhi(gv.z), a[5]);  \
    a[6] = fmaf(q, bflo(gv.w), a[6]); a[7] = fmaf(q, bfhi(gv.w), a[7]);

__global__ __launch_bounds__(256) void spmm2_kernel(
    BrArgs A, BrArgs B, const float* __restrict__ fW, int k,
    float* __restrict__ z2, int storeH, int n)
{
    const int bid = blockIdx.x;
    const int br = bid & 1;
    const int wv = threadIdx.x >> 6;
    const int r0 = (bid >> 1) * 8 + wv * 2;
    if (r0 >= n) return;
    const int r1 = r0 + 1;
    const bool has1 = (r1 < n);
    const int*   rowp = br ? B.rowp : A.rowp;
    const int2*  cwp  = br ? B.cw   : A.cw;
    const uint*  hin  = br ? B.hin  : A.hin;
    uint*        hout = br ? B.hout : A.hout;
    const float* Wo   = br ? B.Wo   : A.Wo;
    const int lane = threadIdx.x & 63;
    const int g   = lane >> 4;
    const int sub = lane & 15;
    const uint subB = (uint)sub * 16u;
    const char* hbase = (const char*)hin;

    const int sA = rowp[r0], eA = rowp[r0 + 1];
    const int sB = has1 ? rowp[r1] : 0, eB = has1 ? rowp[r1 + 1] : 0;

    float aA[8], aB[8];
#pragma unroll
    for (int j = 0; j < 8; ++j) { aA[j] = 0.f; aB[j] = 0.f; }

    int iA = sA, iB = sB;

    // both rows active: 8 dwordx4 gathers in flight
    while (iA < eA && iB < eB) {
        const int2 mA0 = cwp[iA + g];      const int2 mA1 = cwp[iA + 4 + g];
        const int2 mA2 = cwp[iA + 8 + g];  const int2 mA3 = cwp[iA + 12 + g];
        const int2 mB0 = cwp[iB + g];      const int2 mB1 = cwp[iB + 4 + g];
        const int2 mB2 = cwp[iB + 8 + g];  const int2 mB3 = cwp[iB + 12 + g];
        const uint4 gA0 = *(const uint4*)(hbase + ((uint)mA0.x + subB));
        const uint4 gA1 = *(const uint4*)(hbase + ((uint)mA1.x + subB));
        const uint4 gA2 = *(const uint4*)(hbase + ((uint)mA2.x + subB));
        const uint4 gA3 = *(const uint4*)(hbase + ((uint)mA3.x + subB));
        const uint4 gB0 = *(const uint4*)(hbase + ((uint)mB0.x + subB));
        const uint4 gB1 = *(const uint4*)(hbase + ((uint)mB1.x + subB));
        const uint4 gB2 = *(const uint4*)(hbase + ((uint)mB2.x + subB));
        const uint4 gB3 = *(const uint4*)(hbase + ((uint)mB3.x + subB));
        FMA8(aA, gA0, __int_as_float(mA0.y));
        FMA8(aA, gA1, __int_as_float(mA1.y));
        FMA8(aA, gA2, __int_as_float(mA2.y));
        FMA8(aA, gA3, __int_as_float(mA3.y));
        FMA8(aB, gB0, __int_as_float(mB0.y));
        FMA8(aB, gB1, __int_as_float(mB1.y));
        FMA8(aB, gB2, __int_as_float(mB2.y));
        FMA8(aB, gB3, __int_as_float(mB3.y));
        iA += 16; iB += 16;
    }
    while (iA < eA) {
        const int2 m0 = cwp[iA + g];      const int2 m1 = cwp[iA + 4 + g];
        const int2 m2 = cwp[iA + 8 + g];  const int2 m3 = cwp[iA + 12 + g];
        const uint4 g0 = *(const uint4*)(hbase + ((uint)m0.x + subB));
        const uint4 g1 = *(const uint4*)(hbase + ((uint)m1.x + subB));
        const uint4 g2 = *(const uint4*)(hbase + ((uint)m2.x + subB));
        const uint4 g3 = *(const uint4*)(hbase + ((uint)m3.x + subB));
        FMA8(aA, g0, __int_as_float(m0.y));
        FMA8(aA, g1, __int_as_float(m1.y));
        FMA8(aA, g2, __int_as_float(m2.y));
        FMA8(aA, g3, __int_as_float(m3.y));
        iA += 16;
    }
    while (iB < eB) {
        const int2 m0 = cwp[iB + g];      const int2 m1 = cwp[iB + 4 + g];
        const int2 m2 = cwp[iB + 8 + g];  const int2 m3 = cwp[iB + 12 + g];
        const uint4 g0 = *(const uint4*)(hbase + ((uint)m0.x + subB));
        const uint4 g1 = *(const uint4*)(hbase + ((uint)m1.x + subB));
        const uint4 g2 = *(const uint4*)(hbase + ((uint)m2.x + subB));
        const uint4 g3 = *(const uint4*)(hbase + ((uint)m3.x + subB));
        FMA8(aB, g0, __int_as_float(m0.y));
        FMA8(aB, g1, __int_as_float(m1.y));
        FMA8(aB, g2, __int_as_float(m2.y));
        FMA8(aB, g3, __int_as_float(m3.y));
        iB += 16;
    }

    // sum the 4 quad groups -> every lane holds full sums for its 8 features
#pragma unroll
    for (int j = 0; j < 8; ++j) {
        aA[j] += __shfl_xor(aA[j], 16);
        aA[j] += __shfl_xor(aA[j], 32);
        aB[j] += __shfl_xor(aB[j], 16);
        aB[j] += __shfl_xor(aB[j], 32);
    }

    if (storeH && g == 0) {
        uint4 oA;
        oA.x = packbf(aA[0], aA[1]); oA.y = packbf(aA[2], aA[3]);
        oA.z = packbf(aA[4], aA[5]); oA.w = packbf(aA[6], aA[7]);
        *(uint4*)((char*)hout + (size_t)r0 * 256 + subB) = oA;
        if (has1) {
            uint4 oB;
            oB.x = packbf(aB[0], aB[1]); oB.y = packbf(aB[2], aB[3]);
            oB.z = packbf(aB[4], aB[5]); oB.w = packbf(aB[6], aB[7]);
            *(uint4*)((char*)hout + (size_t)r1 * 256 + subB) = oB;
        }
    }

    // projection: group g covers classes g*3..g*3+2, reduce over 16 sub-lanes
    float wv3[8][3];
#pragma unroll
    for (int j = 0; j < 8; ++j)
#pragma unroll
        for (int s2 = 0; s2 < 3; ++s2) {
            const int c = g * 3 + s2;
            wv3[j][s2] = (c < COUT) ? Wo[(size_t)(sub * 8 + j) * COUT + c] : 0.f;
        }
    float zA[3] = {0.f, 0.f, 0.f}, zB[3] = {0.f, 0.f, 0.f};
#pragma unroll
    for (int j = 0; j < 8; ++j) {
#pragma unroll
        for (int s2 = 0; s2 < 3; ++s2) {
            zA[s2] = fmaf(aA[j], wv3[j][s2], zA[s2]);
            zB[s2] = fmaf(aB[j], wv3[j][s2], zB[s2]);
        }
    }
#pragma unroll
    for (int off = 8; off; off >>= 1) {
#pragma unroll
        for (int s2 = 0; s2 < 3; ++s2) {
            zA[s2] += __shfl_xor(zA[s2], off);
            zB[s2] += __shfl_xor(zB[s2], off);
        }
    }
    const int c = g * 3 + sub;
    if (sub < 3 && c < COUT) {
        const float fw = fW[br * (KHOPS + 1) + k + 1];
        const float zselA = (sub == 0) ? zA[0] : (sub == 1) ? zA[1] : zA[2];
        z2[(size_t)r0 * (2 * COUT) + br * COUT + c] += fw * zselA;
        if (has1) {
            const float zselB = (sub == 0) ? zB[0] : (sub == 1) ? zB[1] : zB[2];
            z2[(size_t)r1 * (2 * COUT) + br * COUT + c] += fw * zselB;
        }
    }
}

// ---------------- z2 init: fw0 * (h0 @ Wout) per branch ----------------
__global__ __launch_bounds__(256) void zacc2_kernel(
    const uint* __restrict__ h1, const uint* __restrict__ h2,
    const float* __restrict__ Wout, const float* __restrict__ fW,
    float* __restrict__ z2, int n)
{
    const int wid = (blockIdx.x * blockDim.x + threadIdx.x) >> 6;
    if (wid >= n) return;
    const int lane = threadIdx.x & 63;
    const uint u1 = h1[(size_t)wid * 64 + lane];
    const uint u2 = h2[(size_t)wid * 64 + lane];
    const float a1 = bflo(u1), b1v = bfhi(u1);
    const float a2 = bflo(u2), b2v = bfhi(u2);
    const float* wp1 = Wout + (size_t)(lane * 2) * COUT;
    const float* wp2 = Wout + (size_t)HID * COUT + (size_t)(lane * 2) * COUT;
    float zv1 = 0.f, zv2 = 0.f;
#pragma unroll
    for (int c = 0; c < COUT; ++c) {
        float p1 = fmaf(a1, wp1[c], b1v * wp1[COUT + c]);
        float p2 = fmaf(a2, wp2[c], b2v * wp2[COUT + c]);
#pragma unroll
        for (int off = 32; off; off >>= 1) { p1 += __shfl_xor(p1, off); p2 += __shfl_xor(p2, off); }
        if (lane == c) { zv1 = p1; zv2 = p2; }
    }
    if (lane < COUT) {
        z2[(size_t)wid * (2 * COUT) + lane]        = fW[0] * zv1;
        z2[(size_t)wid * (2 * COUT) + COUT + lane] = fW[KHOPS + 1] * zv2;
    }
}

// ---------------- log_softmax(z2_br0 + z2_br1 + bias) ----------------
__global__ void logsm_kernel(const float* __restrict__ z2, const float* __restrict__ bout,
                             float* __restrict__ out, int n)
{
    const int r = blockIdx.x * blockDim.x + threadIdx.x;
    if (r >= n) return;
    float v[COUT];
    float m = -1e30f;
#pragma unroll
    for (int c = 0; c < COUT; ++c) {
        v[c] = z2[(size_t)r * (2 * COUT) + c] + z2[(size_t)r * (2 * COUT) + COUT + c] + bout[c];
        m = fmaxf(m, v[c]);
    }
    float s = 0.f;
#pragma unroll
    for (int c = 0; c < COUT; ++c) s += expf(v[c] - m);
    const float l = logf(s) + m;
#pragma unroll
    for (int c = 0; c < COUT; ++c) out[(size_t)r * COUT + c] = v[c] - l;
}

extern "C" void kernel_launch(void* const* d_in, const int* in_sizes, int n_in,
                              void* d_out, int out_size, void* d_ws, size_t ws_size,
                              hipStream_t stream)
{
    const float* x    = (const float*)d_in[0];
    const int*   ei1  = (const int*)d_in[1];
    const float* ew1  = (const float*)d_in[2];
    const int*   ei2  = (const int*)d_in[3];
    const float* ew2  = (const float*)d_in[4];
    const float* Win  = (const float*)d_in[5];
    const float* bin  = (const float*)d_in[6];
    const float* fW   = (const float*)d_in[7];
    const float* Wout = (const float*)d_in[8];
    const float* bout = (const float*)d_in[9];
    const int n  = in_sizes[0] / F_IN;
    const int E1 = in_sizes[2];
    const int E2 = in_sizes[4];
    const int Emax = E1 > E2 ? E1 : E2;
    const int nb = (n + 63) / 64;
    float* zout = (float*)d_out;

    char* p = (char*)d_ws;
    auto alloc = [&](size_t bytes) { char* r = p; p += (bytes + 255) & ~(size_t)255; return r; };
    char* regA = alloc((size_t)4 * n * 64 * 4);
    uint* h1A = (uint*)regA;
    uint* h1B = (uint*)(regA + (size_t)n * 64 * 4);
    uint* h2A = (uint*)(regA + (size_t)2 * n * 64 * 4);
    uint* h2B = (uint*)(regA + (size_t)3 * n * 64 * 4);
    int2* tcw1 = (int2*)regA;
    int2* tcw2 = (int2*)(regA + (size_t)Emax * 8);
    const size_t cwCap = (size_t)Emax + 16 * (size_t)n + 64;   // padded capacity
    int2* cw1  = (int2*)alloc(cwCap * 8);
    int2* cw2  = (int2*)alloc(cwCap * 8);
    int*  rowp1 = (int*)alloc((size_t)(n + 1) * 4);
    int*  rowp2 = (int*)alloc((size_t)(n + 1) * 4);
    float* z2  = (float*)alloc((size_t)n * 2 * COUT * 4);
    int*  rcnt  = (int*)alloc((size_t)2 * n * 4);
    int*  bbase = (int*)alloc((size_t)2 * (nb + 1) * 4);
    int*  bcur  = (int*)alloc((size_t)2 * nb * 4);
    ushort* Wsw = (ushort*)alloc((size_t)2 * 16 * 8 * 64 * 8 * 2);

    const int rowBlocks = (n + 3) / 4;

    hipLaunchKernelGGL(wprep_kernel, dim3(64), dim3(256), 0, stream, Win, Wsw);

    hipMemsetAsync(rcnt, 0, (size_t)2 * n * 4, stream);
    hipLaunchKernelGGL(bhist2_kernel, dim3(1024, 2), dim3(256), 0, stream,
                       ei1, E1, ei2, E2, rcnt, n);
    hipLaunchKernelGGL(scan2_kernel, dim3(1, 2), dim3(256), 0, stream,
                       rcnt, rowp1, rowp2, bbase, bcur, n, nb, E1, E2);
    hipLaunchKernelGGL(bscat_kernel, dim3(SCAT_BLOCKS, 2), dim3(256), 2 * nb * 4, stream,
                       ei1, ei1 + E1, ew1, E1, ei2, ei2 + E2, ew2, E2,
                       bcur, tcw1, tcw2, nb);
    hipLaunchKernelGGL(bsort_kernel, dim3(nb, 2), dim3(256), 0, stream,
                       bbase, tcw1, tcw2, rowp1, rowp2, cw1, cw2, nb, n);

    hipLaunchKernelGGL(gemm_mfma_kernel, dim3((n + 127) / 128, 2), dim3(256), 0, stream,
                       x, Wsw, bin, h1A, h2A, n);

    hipLaunchKernelGGL(zacc2_kernel, dim3(rowBlocks), dim3(256), 0, stream,
                       h1A, h2A, Wout, fW, z2, n);

    uint* cur1 = h1A; uint* nxt1 = h1B;
    uint* cur2 = h2A; uint* nxt2 = h2B;
    const int spmmBlocks = ((n + 7) / 8) * 2;
    for (int k = 0; k < KHOPS; ++k) {
        const int storeH = (k < KHOPS - 1) ? 1 : 0;
        BrArgs A { rowp1, cw1, cur1, nxt1, Wout };
        BrArgs B { rowp2, cw2, cur2, nxt2, Wout + (size_t)HID * COUT };
        hipLaunchKernelGGL(spmm2_kernel, dim3(spmmBlocks), dim3(256), 0, stream,
                           A, B, fW, k, z2, storeH, n);
        uint* t1 = cur1; cur1 = nxt1; nxt1 = t1;
        uint* t2 = cur2; cur2 = nxt2; nxt2 = t2;
    }

    hipLaunchKernelGGL(logsm_kernel, dim3((n + 255) / 256), dim3(256), 0, stream,
                       z2, bout, zout, n);
}

// Round 11
// 2968.761 us; speedup vs baseline: 1.4566x; 1.4566x over previous
//
#include <hip/hip_runtime.h>

#define F_IN 512
#define HID 128
#define KHOPS 10
#define COUT 10

typedef unsigned int uint;
typedef unsigned short ushort;
typedef float f32x4 __attribute__((ext_vector_type(4)));
typedef short bf16x8 __attribute__((ext_vector_type(8)));

__device__ __forceinline__ uint f2bf1(float f) {
    uint u = __float_as_uint(f);
    return (u + 0x7fffu + ((u >> 16) & 1u)) >> 16;   // RNE
}
__device__ __forceinline__ uint packbf(float a, float b) {
    return f2bf1(a) | (f2bf1(b) << 16);
}
__device__ __forceinline__ float bflo(uint u) { return __uint_as_float(u << 16); }
__device__ __forceinline__ float bfhi(uint u) { return __uint_as_float(u & 0xffff0000u); }
__device__ __forceinline__ int pad4i(int c) { return (c + 3) & ~3; }

// ---------------- W_in -> bf16, pre-swizzled into MFMA B-fragment lane order ----------------
__global__ __launch_bounds__(256) void wprep_kernel(
    const float* __restrict__ Win, ushort* __restrict__ Wsw)
{
    const int t = blockIdx.x * blockDim.x + threadIdx.x;
    if (t >= 2 * 16 * 8 * 64) return;
    const int l = t & 63;
    const int c = (t >> 6) & 7;
    const int s = (t >> 9) & 15;
    const int br = t >> 13;
    const int col = c * 16 + (l & 15);
    const int k0 = s * 32 + (l >> 4) * 8;
    const float* W = Win + (size_t)br * F_IN * HID;
    uint o0 = packbf(W[(size_t)(k0 + 0) * HID + col], W[(size_t)(k0 + 1) * HID + col]);
    uint o1 = packbf(W[(size_t)(k0 + 2) * HID + col], W[(size_t)(k0 + 3) * HID + col]);
    uint o2 = packbf(W[(size_t)(k0 + 4) * HID + col], W[(size_t)(k0 + 5) * HID + col]);
    uint o3 = packbf(W[(size_t)(k0 + 6) * HID + col], W[(size_t)(k0 + 7) * HID + col]);
    *(uint4*)(Wsw + (size_t)t * 8) = make_uint4(o0, o1, o2, o3);
}

// ---------------- GEMM via MFMA: h = bf16(x @ W + b) ----------------
__global__ __launch_bounds__(256) void gemm_mfma_kernel(
    const float* __restrict__ x, const ushort* __restrict__ Wsw,
    const float* __restrict__ bin, uint* __restrict__ h1, uint* __restrict__ h2, int n)
{
    const int br = blockIdx.y;
    const uint4* Wb = (const uint4*)(Wsw + (size_t)br * 16 * 8 * 64 * 8);
    const float* bias = bin + br * HID;
    uint* h = br ? h2 : h1;

    const int w = threadIdx.x >> 6;
    const int lane = threadIdx.x & 63;
    const int r16 = lane & 15;
    const int kg = lane >> 4;

    const int rowbase = blockIdx.x * 128 + w * 32;

    f32x4 acc[2][8];
#pragma unroll
    for (int f = 0; f < 2; ++f)
#pragma unroll
        for (int c = 0; c < 8; ++c) acc[f][c] = (f32x4)0.f;

    int rA0 = rowbase + r16;      if (rA0 > n - 1) rA0 = n - 1;
    int rA1 = rowbase + 16 + r16; if (rA1 > n - 1) rA1 = n - 1;
    const float* xp0 = x + (size_t)rA0 * F_IN + kg * 8;
    const float* xp1 = x + (size_t)rA1 * F_IN + kg * 8;

    for (int s = 0; s < 16; ++s) {
        const float4 a0lo = *(const float4*)(xp0 + s * 32);
        const float4 a0hi = *(const float4*)(xp0 + s * 32 + 4);
        const float4 a1lo = *(const float4*)(xp1 + s * 32);
        const float4 a1hi = *(const float4*)(xp1 + s * 32 + 4);
        union { uint4 u; bf16x8 v; } af0, af1;
        af0.u = make_uint4(packbf(a0lo.x, a0lo.y), packbf(a0lo.z, a0lo.w),
                           packbf(a0hi.x, a0hi.y), packbf(a0hi.z, a0hi.w));
        af1.u = make_uint4(packbf(a1lo.x, a1lo.y), packbf(a1lo.z, a1lo.w),
                           packbf(a1hi.x, a1hi.y), packbf(a1hi.z, a1hi.w));
        const uint4* wq = Wb + (size_t)(s * 8) * 64 + lane;
#pragma unroll
        for (int c = 0; c < 8; ++c) {
            union { uint4 u; bf16x8 v; } bfr;
            bfr.u = wq[c * 64];
            acc[0][c] = __builtin_amdgcn_mfma_f32_16x16x32_bf16(af0.v, bfr.v, acc[0][c], 0, 0, 0);
            acc[1][c] = __builtin_amdgcn_mfma_f32_16x16x32_bf16(af1.v, bfr.v, acc[1][c], 0, 0, 0);
        }
    }

    float bv[8];
#pragma unroll
    for (int c = 0; c < 8; ++c) bv[c] = bias[c * 16 + r16];

#pragma unroll
    for (int f = 0; f < 2; ++f)
#pragma unroll
        for (int c = 0; c < 8; ++c)
#pragma unroll
            for (int i = 0; i < 4; ++i) {
                const float v = acc[f][c][i] + bv[c];
                const float o = __shfl_xor(v, 1);
                const int row = rowbase + f * 16 + kg * 4 + i;
                if (!(lane & 1) && row < n)
                    h[(size_t)row * 64 + c * 8 + (r16 >> 1)] = packbf(v, o);
            }
}

// ---------------- CSR build (rows padded to multiple of 4) ----------------
// temp record: lo = (col << 8) | rowlocal, hi = w bits
// final cw record: lo = col*256 byte offset, hi = w bits; pads = (0,0)

__global__ void bhist2_kernel(const int* __restrict__ r1, int E1,
                              const int* __restrict__ r2, int E2,
                              int* __restrict__ rcnt, int n)
{
    const int br = blockIdx.y;
    const int* rows = br ? r2 : r1;
    const int E = br ? E2 : E1;
    int* rc = rcnt + (size_t)br * n;
    for (int i = blockIdx.x * blockDim.x + threadIdx.x; i < E; i += gridDim.x * blockDim.x)
        atomicAdd(&rc[rows[i]], 1);
}

#define SCAN_CHUNK 448   // multiple of 64, 256*448 >= n
__global__ __launch_bounds__(256) void scan2_kernel(
    const int* __restrict__ rcnt, int* __restrict__ rowp1, int* __restrict__ rowp2,
    int* __restrict__ bbase, int* __restrict__ bcur,
    int n, int nb, int E1, int E2)
{
    __shared__ int spad[256], sunp[256];
    const int br = blockIdx.y;
    const int* rc = rcnt + (size_t)br * n;
    int* rowp = br ? rowp2 : rowp1;
    int* bb = bbase + (size_t)br * (nb + 1);
    int* cur = bcur + (size_t)br * nb;
    const int E = br ? E2 : E1;
    const int t = threadIdx.x;
    const int start = t * SCAN_CHUNK;
    const int end = (start + SCAN_CHUNK < n) ? start + SCAN_CHUNK : n;
    int sp = 0, su = 0;
    for (int i = start; i < end; ++i) { int c = rc[i]; sp += pad4i(c); su += c; }
    spad[t] = sp; sunp[t] = su;
    __syncthreads();
    if (t == 0) {
        int rp = 0, up = 0;
        for (int i = 0; i < 256; ++i) {
            int a = spad[i], b = sunp[i];
            spad[i] = rp; sunp[i] = up;
            rp += a; up += b;
        }
        rowp[n] = rp;       // padded total
        bb[nb] = E;
    }
    __syncthreads();
    int rp = spad[t];
    for (int i = start; i < end; ++i) { rowp[i] = rp; rp += pad4i(rc[i]); }
    int up = sunp[t];
    for (int b = start >> 6; b < (end + 63) >> 6; ++b) {
        bb[b] = up; cur[b] = up;
        const int rend = (b * 64 + 64 < n) ? b * 64 + 64 : n;
        for (int r = b * 64; r < rend; ++r) up += rc[r];
    }
}

#define SCAT_BLOCKS 256
__global__ __launch_bounds__(256) void bscat_kernel(
    const int* __restrict__ r1, const int* __restrict__ c1, const float* __restrict__ w1, int E1,
    const int* __restrict__ r2, const int* __restrict__ c2, const float* __restrict__ w2, int E2,
    int* __restrict__ bcur, int2* __restrict__ t1, int2* __restrict__ t2, int nb)
{
    extern __shared__ int sh[];
    int* lh = sh;
    int* lbase = sh + nb;
    const int br = blockIdx.y;
    const int* rows = br ? r2 : r1;
    const int* cols = br ? c2 : c1;
    const float* w  = br ? w2 : w1;
    const int E = br ? E2 : E1;
    int* cur = bcur + (size_t)br * nb;
    int2* tcw = br ? t2 : t1;
    const int t = threadIdx.x;

    for (int i = t; i < nb; i += 256) lh[i] = 0;
    __syncthreads();

    const int per = (E + SCAT_BLOCKS - 1) / SCAT_BLOCKS;
    const int c0 = blockIdx.x * per;
    const int cend = (c0 + per < E) ? c0 + per : E;

    for (int i = c0 + t; i < cend; i += 256)
        atomicAdd(&lh[rows[i] >> 6], 1);
    __syncthreads();
    for (int b = t; b < nb; b += 256) {
        int c = lh[b];
        lbase[b] = c ? atomicAdd(&cur[b], c) : 0;
        lh[b] = 0;
    }
    __syncthreads();
    for (int i = c0 + t; i < cend; i += 256) {
        int r = rows[i];
        int b = r >> 6;
        int p = atomicAdd(&lh[b], 1);
        uint lo = ((uint)cols[i] << 8) | (uint)(r & 63);
        tcw[lbase[b] + p] = make_int2((int)lo, __float_as_int(w[i]));
    }
}

// counting place into padded final positions + zero-fill pads
__global__ __launch_bounds__(256) void bsort_kernel(
    const int* __restrict__ bbase,
    const int2* __restrict__ t1, const int2* __restrict__ t2,
    const int* __restrict__ rowp1, const int* __restrict__ rowp2,
    int2* __restrict__ cw1, int2* __restrict__ cw2, int nb, int n)
{
    __shared__ int pos[64];
    const int br = blockIdx.y;
    const int* bb = bbase + (size_t)br * (nb + 1);
    const int2* tcw = br ? t2 : t1;
    const int* rowp = br ? rowp2 : rowp1;
    int2* cw = br ? cw2 : cw1;
    const int b = blockIdx.x;
    const int t = threadIdx.x;
    const int base = bb[b];
    const int m = bb[b + 1] - base;
    if (t < 64) {
        const int g = b * 64 + t;
        pos[t] = (g < n) ? rowp[g] : 0;
    }
    __syncthreads();
    for (int i = t; i < m; i += 256) {
        int2 e = tcw[base + i];
        int r = (uint)e.x & 63;
        int p = atomicAdd(&pos[r], 1);
        cw[p] = make_int2((int)((uint)e.x & 0xFFFFFF00u), e.y);
    }
    __syncthreads();
    if (t < 64) {
        const int g = b * 64 + t;
        if (g < n) {
            const int pend = rowp[g + 1];
            for (int p = pos[t]; p < pend; ++p) cw[p] = make_int2(0, 0);  // pad edges
        }
    }
}

// ---------------- SpMM: 2 rows/wave, maskless 4-step, readlane metadata ----------------
struct BrArgs {
    const int* rowp;
    const int2* cw;
    const uint* hin;
    uint* hout;
    const float* Wo;
};

__global__ __launch_bounds__(256) void spmm2_kernel(
    BrArgs A, BrArgs B, const float* __restrict__ fW, int k,
    float* __restrict__ z2, int storeH, int n)
{
    const int bid = blockIdx.x;
    const int br = bid & 1;
    const int wv = threadIdx.x >> 6;
    const int r0 = (bid >> 1) * 8 + wv * 2;
    if (r0 >= n) return;
    const int r1 = r0 + 1;
    const bool has1 = (r1 < n);
    const int*   rowp = br ? B.rowp : A.rowp;
    const int2*  cwp  = br ? B.cw   : A.cw;
    const uint*  hin  = br ? B.hin  : A.hin;
    uint*        hout = br ? B.hout : A.hout;
    const float* Wo   = br ? B.Wo   : A.Wo;
    const int lane = threadIdx.x & 63;
    const uint laneB = (uint)lane * 4u;
    const char* hbase = (const char*)hin;

    float w0[COUT], w1[COUT];
    const float* wp = Wo + (size_t)(lane * 2) * COUT;
#pragma unroll
    for (int c = 0; c < COUT; ++c) { w0[c] = wp[c]; w1[c] = wp[COUT + c]; }

    int sA = rowp[r0], eA = rowp[r0 + 1];
    int sB = has1 ? rowp[r1] : 0, eB = has1 ? rowp[r1 + 1] : 0;
    sA = __builtin_amdgcn_readfirstlane(sA);
    eA = __builtin_amdgcn_readfirstlane(eA);
    sB = __builtin_amdgcn_readfirstlane(sB);
    eB = __builtin_amdgcn_readfirstlane(eB);

    float2 accA = make_float2(0.f, 0.f);
    float2 accB = make_float2(0.f, 0.f);
    int iA = sA, iB = sB;

    // all row lengths are multiples of 4 (padded); chunk = up to 64 edges/row
    while (iA < eA || iB < eB) {
        int cA = eA - iA; cA = cA > 64 ? 64 : cA;
        int cB = eB - iB; cB = cB > 64 ? 64 : cB;
        int2 myA = make_int2(0, 0), myB = make_int2(0, 0);
        if (lane < cA) myA = cwp[iA + lane];
        if (lane < cB) myB = cwp[iB + lane];
        const int m = cA < cB ? cA : cB;
        int j = 0;
        // joint phase: 8 gathers in flight, no masks
        for (; j < m; j += 4) {
#pragma unroll
            for (int t2 = 0; t2 < 4; ++t2) { (void)t2; }
            const uint bA0 = (uint)__builtin_amdgcn_readlane(myA.x, j);
            const float qA0 = __int_as_float(__builtin_amdgcn_readlane(myA.y, j));
            const uint bA1 = (uint)__builtin_amdgcn_readlane(myA.x, j + 1);
            const float qA1 = __int_as_float(__builtin_amdgcn_readlane(myA.y, j + 1));
            const uint bA2 = (uint)__builtin_amdgcn_readlane(myA.x, j + 2);
            const float qA2 = __int_as_float(__builtin_amdgcn_readlane(myA.y, j + 2));
            const uint bA3 = (uint)__builtin_amdgcn_readlane(myA.x, j + 3);
            const float qA3 = __int_as_float(__builtin_amdgcn_readlane(myA.y, j + 3));
            const uint bB0 = (uint)__builtin_amdgcn_readlane(myB.x, j);
            const float qB0 = __int_as_float(__builtin_amdgcn_readlane(myB.y, j));
            const uint bB1 = (uint)__builtin_amdgcn_readlane(myB.x, j + 1);
            const float qB1 = __int_as_float(__builtin_amdgcn_readlane(myB.y, j + 1));
            const uint bB2 = (uint)__builtin_amdgcn_readlane(myB.x, j + 2);
            const float qB2 = __int_as_float(__builtin_amdgcn_readlane(myB.y, j + 2));
            const uint bB3 = (uint)__builtin_amdgcn_readlane(myB.x, j + 3);
            const float qB3 = __int_as_float(__builtin_amdgcn_readlane(myB.y, j + 3));
            const uint gA0 = *(const uint*)(hbase + (size_t)bA0 + laneB);
            const uint gB0 = *(const uint*)(hbase + (size_t)bB0 + laneB);
            const uint gA1 = *(const uint*)(hbase + (size_t)bA1 + laneB);
            const uint gB1 = *(const uint*)(hbase + (size_t)bB1 + laneB);
            const uint gA2 = *(const uint*)(hbase + (size_t)bA2 + laneB);
            const uint gB2 = *(const uint*)(hbase + (size_t)bB2 + laneB);
            const uint gA3 = *(const uint*)(hbase + (size_t)bA3 + laneB);
            const uint gB3 = *(const uint*)(hbase + (size_t)bB3 + laneB);
            accA.x = fmaf(qA0, bflo(gA0), accA.x); accA.y = fmaf(qA0, bfhi(gA0), accA.y);
            accB.x = fmaf(qB0, bflo(gB0), accB.x); accB.y = fmaf(qB0, bfhi(gB0), accB.y);
            accA.x = fmaf(qA1, bflo(gA1), accA.x); accA.y = fmaf(qA1, bfhi(gA1), accA.y);
            accB.x = fmaf(qB1, bflo(gB1), accB.x); accB.y = fmaf(qB1, bfhi(gB1), accB.y);
            accA.x = fmaf(qA2, bflo(gA2), accA.x); accA.y = fmaf(qA2, bfhi(gA2), accA.y);
            accB.x = fmaf(qB2, bflo(gB2), accB.x); accB.y = fmaf(qB2, bfhi(gB2), accB.y);
            accA.x = fmaf(qA3, bflo(gA3), accA.x); accA.y = fmaf(qA3, bfhi(gA3), accA.y);
            accB.x = fmaf(qB3, bflo(gB3), accB.x); accB.y = fmaf(qB3, bfhi(gB3), accB.y);
        }
        // remainder of the longer row in this chunk: 4 gathers in flight
        for (; j < cA; j += 4) {
            const uint b0 = (uint)__builtin_amdgcn_readlane(myA.x, j);
            const float q0 = __int_as_float(__builtin_amdgcn_readlane(myA.y, j));
            const uint b1 = (uint)__builtin_amdgcn_readlane(myA.x, j + 1);
            const float q1 = __int_as_float(__builtin_amdgcn_readlane(myA.y, j + 1));
            const uint b2 = (uint)__builtin_amdgcn_readlane(myA.x, j + 2);
            const float q2 = __int_as_float(__builtin_amdgcn_readlane(myA.y, j + 2));
            const uint b3 = (uint)__builtin_amdgcn_readlane(myA.x, j + 3);
            const float q3 = __int_as_float(__builtin_amdgcn_readlane(myA.y, j + 3));
            const uint g0 = *(const uint*)(hbase + (size_t)b0 + laneB);
            const uint g1 = *(const uint*)(hbase + (size_t)b1 + laneB);
            const uint g2 = *(const uint*)(hbase + (size_t)b2 + laneB);
            const uint g3 = *(const uint*)(hbase + (size_t)b3 + laneB);
            accA.x = fmaf(q0, bflo(g0), accA.x); accA.y = fmaf(q0, bfhi(g0), accA.y);
            accA.x = fmaf(q1, bflo(g1), accA.x); accA.y = fmaf(q1, bfhi(g1), accA.y);
            accA.x = fmaf(q2, bflo(g2), accA.x); accA.y = fmaf(q2, bfhi(g2), accA.y);
            accA.x = fmaf(q3, bflo(g3), accA.x); accA.y = fmaf(q3, bfhi(g3), accA.y);
        }
        for (; j < cB; j += 4) {
            const uint b0 = (uint)__builtin_amdgcn_readlane(myB.x, j);
            const float q0 = __int_as_float(__builtin_amdgcn_readlane(myB.y, j));
            const uint b1 = (uint)__builtin_amdgcn_readlane(myB.x, j + 1);
            const float q1 = __int_as_float(__builtin_amdgcn_readlane(myB.y, j + 1));
            const uint b2 = (uint)__builtin_amdgcn_readlane(myB.x, j + 2);
            const float q2 = __int_as_float(__builtin_amdgcn_readlane(myB.y, j + 2));
            const uint b3 = (uint)__builtin_amdgcn_readlane(myB.x, j + 3);
            const float q3 = __int_as_float(__builtin_amdgcn_readlane(myB.y, j + 3));
            const uint g0 = *(const uint*)(hbase + (size_t)b0 + laneB);
            const uint g1 = *(const uint*)(hbase + (size_t)b1 + laneB);
            const uint g2 = *(const uint*)(hbase + (size_t)b2 + laneB);
            const uint g3 = *(const uint*)(hbase + (size_t)b3 + laneB);
            accB.x = fmaf(q0, bflo(g0), accB.x); accB.y = fmaf(q0, bfhi(g0), accB.y);
            accB.x = fmaf(q1, bflo(g1), accB.x); accB.y = fmaf(q1, bfhi(g1), accB.y);
            accB.x = fmaf(q2, bflo(g2), accB.x); accB.y = fmaf(q2, bfhi(g2), accB.y);
            accB.x = fmaf(q3, bflo(g3), accB.x); accB.y = fmaf(q3, bfhi(g3), accB.y);
        }
        iA += cA; iB += cB;
    }

    if (storeH) {
        hout[(size_t)r0 * 64 + lane] = packbf(accA.x, accA.y);
        if (has1) hout[(size_t)r1 * 64 + lane] = packbf(accB.x, accB.y);
    }

    const float fw = fW[br * (KHOPS + 1) + k + 1];
    float zA = 0.f, zB = 0.f;
#pragma unroll
    for (int c = 0; c < COUT; ++c) {
        float pA = fmaf(accA.x, w0[c], accA.y * w1[c]);
        float pB = fmaf(accB.x, w0[c], accB.y * w1[c]);
#pragma unroll
        for (int off = 32; off; off >>= 1) { pA += __shfl_xor(pA, off); pB += __shfl_xor(pB, off); }
        if (lane == c) { zA = pA; zB = pB; }
    }
    if (lane < COUT) {
        z2[(size_t)r0 * (2 * COUT) + br * COUT + lane] += fw * zA;
        if (has1) z2[(size_t)r1 * (2 * COUT) + br * COUT + lane] += fw * zB;
    }
}

// ---------------- z2 init: fw0 * (h0 @ Wout) per branch ----------------
__global__ __launch_bounds__(256) void zacc2_kernel(
    const uint* __restrict__ h1, const uint* __restrict__ h2,
    const float* __restrict__ Wout, const float* __restrict__ fW,
    float* __restrict__ z2, int n)
{
    const int wid = (blockIdx.x * blockDim.x + threadIdx.x) >> 6;
    if (wid >= n) return;
    const int lane = threadIdx.x & 63;
    const uint u1 = h1[(size_t)wid * 64 + lane];
    const uint u2 = h2[(size_t)wid * 64 + lane];
    const float a1 = bflo(u1), b1v = bfhi(u1);
    const float a2 = bflo(u2), b2v = bfhi(u2);
    const float* wp1 = Wout + (size_t)(lane * 2) * COUT;
    const float* wp2 = Wout + (size_t)HID * COUT + (size_t)(lane * 2) * COUT;
    float zv1 = 0.f, zv2 = 0.f;
#pragma unroll
    for (int c = 0; c < COUT; ++c) {
        float p1 = fmaf(a1, wp1[c], b1v * wp1[COUT + c]);
        float p2 = fmaf(a2, wp2[c], b2v * wp2[COUT + c]);
#pragma unroll
        for (int off = 32; off; off >>= 1) { p1 += __shfl_xor(p1, off); p2 += __shfl_xor(p2, off); }
        if (lane == c) { zv1 = p1; zv2 = p2; }
    }
    if (lane < COUT) {
        z2[(size_t)wid * (2 * COUT) + lane]        = fW[0] * zv1;
        z2[(size_t)wid * (2 * COUT) + COUT + lane] = fW[KHOPS + 1] * zv2;
    }
}

// ---------------- log_softmax(z2_br0 + z2_br1 + bias) ----------------
__global__ void logsm_kernel(const float* __restrict__ z2, const float* __restrict__ bout,
                             float* __restrict__ out, int n)
{
    const int r = blockIdx.x * blockDim.x + threadIdx.x;
    if (r >= n) return;
    float v[COUT];
    float m = -1e30f;
#pragma unroll
    for (int c = 0; c < COUT; ++c) {
        v[c] = z2[(size_t)r * (2 * COUT) + c] + z2[(size_t)r * (2 * COUT) + COUT + c] + bout[c];
        m = fmaxf(m, v[c]);
    }
    float s = 0.f;
#pragma unroll
    for (int c = 0; c < COUT; ++c) s += expf(v[c] - m);
    const float l = logf(s) + m;
#pragma unroll
    for (int c = 0; c < COUT; ++c) out[(size_t)r * COUT + c] = v[c] - l;
}

extern "C" void kernel_launch(void* const* d_in, const int* in_sizes, int n_in,
                              void* d_out, int out_size, void* d_ws, size_t ws_size,
                              hipStream_t stream)
{
    const float* x    = (const float*)d_in[0];
    const int*   ei1  = (const int*)d_in[1];
    const float* ew1  = (const float*)d_in[2];
    const int*   ei2  = (const int*)d_in[3];
    const float* ew2  = (const float*)d_in[4];
    const float* Win  = (const float*)d_in[5];
    const float* bin  = (const float*)d_in[6];
    const float* fW   = (const float*)d_in[7];
    const float* Wout = (const float*)d_in[8];
    const float* bout = (const float*)d_in[9];
    const int n  = in_sizes[0] / F_IN;
    const int E1 = in_sizes[2];
    const int E2 = in_sizes[4];
    const int Emax = E1 > E2 ? E1 : E2;
    const int nb = (n + 63) / 64;
    float* zout = (float*)d_out;

    char* p = (char*)d_ws;
    auto alloc = [&](size_t bytes) { char* r = p; p += (bytes + 255) & ~(size_t)255; return r; };
    char* regA = alloc((size_t)4 * n * 64 * 4);
    uint* h1A = (uint*)regA;
    uint* h1B = (uint*)(regA + (size_t)n * 64 * 4);
    uint* h2A = (uint*)(regA + (size_t)2 * n * 64 * 4);
    uint* h2B = (uint*)(regA + (size_t)3 * n * 64 * 4);
    int2* tcw1 = (int2*)regA;
    int2* tcw2 = (int2*)(regA + (size_t)Emax * 8);
    const size_t cwCap = (size_t)Emax + 4 * (size_t)n + 64;   // padded capacity
    int2* cw1  = (int2*)alloc(cwCap * 8);
    int2* cw2  = (int2*)alloc(cwCap * 8);
    int*  rowp1 = (int*)alloc((size_t)(n + 1) * 4);
    int*  rowp2 = (int*)alloc((size_t)(n + 1) * 4);
    float* z2  = (float*)alloc((size_t)n * 2 * COUT * 4);
    int*  rcnt  = (int*)alloc((size_t)2 * n * 4);
    int*  bbase = (int*)alloc((size_t)2 * (nb + 1) * 4);
    int*  bcur  = (int*)alloc((size_t)2 * nb * 4);
    ushort* Wsw = (ushort*)alloc((size_t)2 * 16 * 8 * 64 * 8 * 2);

    const int rowBlocks = (n + 3) / 4;

    hipLaunchKernelGGL(wprep_kernel, dim3(64), dim3(256), 0, stream, Win, Wsw);

    hipMemsetAsync(rcnt, 0, (size_t)2 * n * 4, stream);
    hipLaunchKernelGGL(bhist2_kernel, dim3(1024, 2), dim3(256), 0, stream,
                       ei1, E1, ei2, E2, rcnt, n);
    hipLaunchKernelGGL(scan2_kernel, dim3(1, 2), dim3(256), 0, stream,
                       rcnt, rowp1, rowp2, bbase, bcur, n, nb, E1, E2);
    hipLaunchKernelGGL(bscat_kernel, dim3(SCAT_BLOCKS, 2), dim3(256), 2 * nb * 4, stream,
                       ei1, ei1 + E1, ew1, E1, ei2, ei2 + E2, ew2, E2,
                       bcur, tcw1, tcw2, nb);
    hipLaunchKernelGGL(bsort_kernel, dim3(nb, 2), dim3(256), 0, stream,
                       bbase, tcw1, tcw2, rowp1, rowp2, cw1, cw2, nb, n);

    hipLaunchKernelGGL(gemm_mfma_kernel, dim3((n + 127) / 128, 2), dim3(256), 0, stream,
                       x, Wsw, bin, h1A, h2A, n);

    hipLaunchKernelGGL(zacc2_kernel, dim3(rowBlocks), dim3(256), 0, stream,
                       h1A, h2A, Wout, fW, z2, n);

    uint* cur1 = h1A; uint* nxt1 = h1B;
    uint* cur2 = h2A; uint* nxt2 = h2B;
    const int spmmBlocks = ((n + 7) / 8) * 2;
    for (int k = 0; k < KHOPS; ++k) {
        const int storeH = (k < KHOPS - 1) ? 1 : 0;
        BrArgs A { rowp1, cw1, cur1, nxt1, Wout };
        BrArgs B { rowp2, cw2, cur2, nxt2, Wout + (size_t)HID * COUT };
        hipLaunchKernelGGL(spmm2_kernel, dim3(spmmBlocks), dim3(256), 0, stream,
                           A, B, fW, k, z2, storeH, n);
        uint* t1 = cur1; cur1 = nxt1; nxt1 = t1;
        uint* t2 = cur2; cur2 = nxt2; nxt2 = t2;
    }

    hipLaunchKernelGGL(logsm_kernel, dim3((n + 255) / 256), dim3(256), 0, stream,
                       z2, bout, zout, n);
}

// Round 12
// 2831.553 us; speedup vs baseline: 1.5271x; 1.0485x over previous
//
#include <hip/hip_runtime.h>

#define F_IN 512
#define HID 128
#define KHOPS 10
#define COUT 10

typedef unsigned int uint;
typedef unsigned short ushort;
typedef float f32x4 __attribute__((ext_vector_type(4)));
typedef short bf16x8 __attribute__((ext_vector_type(8)));

__device__ __forceinline__ uint f2bf1(float f) {
    uint u = __float_as_uint(f);
    return (u + 0x7fffu + ((u >> 16) & 1u)) >> 16;   // RNE
}
__device__ __forceinline__ uint packbf(float a, float b) {
    return f2bf1(a) | (f2bf1(b) << 16);
}
__device__ __forceinline__ float bflo(uint u) { return __uint_as_float(u << 16); }
__device__ __forceinline__ float bfhi(uint u) { return __uint_as_float(u & 0xffff0000u); }

// ---------------- W_in -> bf16, pre-swizzled into MFMA B-fragment lane order ----------------
__global__ __launch_bounds__(256) void wprep_kernel(
    const float* __restrict__ Win, ushort* __restrict__ Wsw)
{
    const int t = blockIdx.x * blockDim.x + threadIdx.x;
    if (t >= 2 * 16 * 8 * 64) return;
    const int l = t & 63;
    const int c = (t >> 6) & 7;
    const int s = (t >> 9) & 15;
    const int br = t >> 13;
    const int col = c * 16 + (l & 15);
    const int k0 = s * 32 + (l >> 4) * 8;
    const float* W = Win + (size_t)br * F_IN * HID;
    uint o0 = packbf(W[(size_t)(k0 + 0) * HID + col], W[(size_t)(k0 + 1) * HID + col]);
    uint o1 = packbf(W[(size_t)(k0 + 2) * HID + col], W[(size_t)(k0 + 3) * HID + col]);
    uint o2 = packbf(W[(size_t)(k0 + 4) * HID + col], W[(size_t)(k0 + 5) * HID + col]);
    uint o3 = packbf(W[(size_t)(k0 + 6) * HID + col], W[(size_t)(k0 + 7) * HID + col]);
    *(uint4*)(Wsw + (size_t)t * 8) = make_uint4(o0, o1, o2, o3);
}

// ---------------- GEMM via MFMA: h = bf16(x @ W + b) ----------------
__global__ __launch_bounds__(256) void gemm_mfma_kernel(
    const float* __restrict__ x, const ushort* __restrict__ Wsw,
    const float* __restrict__ bin, uint* __restrict__ h1, uint* __restrict__ h2, int n)
{
    const int br = blockIdx.y;
    const uint4* Wb = (const uint4*)(Wsw + (size_t)br * 16 * 8 * 64 * 8);
    const float* bias = bin + br * HID;
    uint* h = br ? h2 : h1;

    const int w = threadIdx.x >> 6;
    const int lane = threadIdx.x & 63;
    const int r16 = lane & 15;
    const int kg = lane >> 4;

    const int rowbase = blockIdx.x * 128 + w * 32;

    f32x4 acc[2][8];
#pragma unroll
    for (int f = 0; f < 2; ++f)
#pragma unroll
        for (int c = 0; c < 8; ++c) acc[f][c] = (f32x4)0.f;

    int rA0 = rowbase + r16;      if (rA0 > n - 1) rA0 = n - 1;
    int rA1 = rowbase + 16 + r16; if (rA1 > n - 1) rA1 = n - 1;
    const float* xp0 = x + (size_t)rA0 * F_IN + kg * 8;
    const float* xp1 = x + (size_t)rA1 * F_IN + kg * 8;

    for (int s = 0; s < 16; ++s) {
        const float4 a0lo = *(const float4*)(xp0 + s * 32);
        const float4 a0hi = *(const float4*)(xp0 + s * 32 + 4);
        const float4 a1lo = *(const float4*)(xp1 + s * 32);
        const float4 a1hi = *(const float4*)(xp1 + s * 32 + 4);
        union { uint4 u; bf16x8 v; } af0, af1;
        af0.u = make_uint4(packbf(a0lo.x, a0lo.y), packbf(a0lo.z, a0lo.w),
                           packbf(a0hi.x, a0hi.y), packbf(a0hi.z, a0hi.w));
        af1.u = make_uint4(packbf(a1lo.x, a1lo.y), packbf(a1lo.z, a1lo.w),
                           packbf(a1hi.x, a1hi.y), packbf(a1hi.z, a1hi.w));
        const uint4* wq = Wb + (size_t)(s * 8) * 64 + lane;
#pragma unroll
        for (int c = 0; c < 8; ++c) {
            union { uint4 u; bf16x8 v; } bfr;
            bfr.u = wq[c * 64];
            acc[0][c] = __builtin_amdgcn_mfma_f32_16x16x32_bf16(af0.v, bfr.v, acc[0][c], 0, 0, 0);
            acc[1][c] = __builtin_amdgcn_mfma_f32_16x16x32_bf16(af1.v, bfr.v, acc[1][c], 0, 0, 0);
        }
    }

    float bv[8];
#pragma unroll
    for (int c = 0; c < 8; ++c) bv[c] = bias[c * 16 + r16];

#pragma unroll
    for (int f = 0; f < 2; ++f)
#pragma unroll
        for (int c = 0; c < 8; ++c)
#pragma unroll
            for (int i = 0; i < 4; ++i) {
                const float v = acc[f][c][i] + bv[c];
                const float o = __shfl_xor(v, 1);
                const int row = rowbase + f * 16 + kg * 4 + i;
                if (!(lane & 1) && row < n)
                    h[(size_t)row * 64 + c * 8 + (r16 >> 1)] = packbf(v, o);
            }
}

// ---------------- CSR build (R9 pipeline) ----------------
// temp record: lo = (col << 8) | rowlocal, hi = w bits
// final cw record: lo = col*256 byte offset, hi = w bits

__global__ void bhist_kernel(const int* __restrict__ r1, int E1,
                             const int* __restrict__ r2, int E2,
                             int* __restrict__ bcnt, int nb)
{
    extern __shared__ int sh[];
    const int br = blockIdx.y;
    const int* rows = br ? r2 : r1;
    const int E = br ? E2 : E1;
    int* bc = bcnt + (size_t)br * nb;
    for (int i = threadIdx.x; i < nb; i += blockDim.x) sh[i] = 0;
    __syncthreads();
    for (int i = blockIdx.x * blockDim.x + threadIdx.x; i < E; i += gridDim.x * blockDim.x)
        atomicAdd(&sh[rows[i] >> 6], 1);
    __syncthreads();
    for (int i = threadIdx.x; i < nb; i += blockDim.x)
        if (sh[i]) atomicAdd(&bc[i], sh[i]);
}

__global__ __launch_bounds__(256) void bscan_kernel(
    const int* __restrict__ bcnt, int* __restrict__ bbase, int* __restrict__ bcur,
    int* __restrict__ rowp1, int* __restrict__ rowp2,
    int nb, int n, int E1, int E2)
{
    __shared__ int ssum[256];
    const int br = blockIdx.y;
    const int* bc = bcnt + (size_t)br * nb;
    int* bb = bbase + (size_t)br * (nb + 1);
    int* cur = bcur + (size_t)br * nb;
    int* rowp = br ? rowp2 : rowp1;
    const int E = br ? E2 : E1;
    const int t = threadIdx.x;
    const int chunk = (nb + 255) / 256;
    const int start = t * chunk;
    const int end = (start + chunk < nb) ? start + chunk : nb;
    int sum = 0;
    for (int i = start; i < end; ++i) sum += bc[i];
    ssum[t] = sum;
    __syncthreads();
    if (t == 0) {
        int run = 0;
        for (int i = 0; i < 256; ++i) { int v = ssum[i]; ssum[i] = run; run += v; }
        bb[nb] = E;
        rowp[n] = E;
    }
    __syncthreads();
    int run = ssum[t];
    for (int i = start; i < end; ++i) {
        bb[i] = run; cur[i] = run; run += bc[i];
    }
}

#define SCAT_BLOCKS 256
__global__ __launch_bounds__(256) void bscat_kernel(
    const int* __restrict__ r1, const int* __restrict__ c1, const float* __restrict__ w1, int E1,
    const int* __restrict__ r2, const int* __restrict__ c2, const float* __restrict__ w2, int E2,
    int* __restrict__ bcur, int2* __restrict__ t1, int2* __restrict__ t2, int nb)
{
    extern __shared__ int sh[];
    int* lh = sh;
    int* lbase = sh + nb;
    const int br = blockIdx.y;
    const int* rows = br ? r2 : r1;
    const int* cols = br ? c2 : c1;
    const float* w  = br ? w2 : w1;
    const int E = br ? E2 : E1;
    int* cur = bcur + (size_t)br * nb;
    int2* tcw = br ? t2 : t1;
    const int t = threadIdx.x;

    for (int i = t; i < nb; i += 256) lh[i] = 0;
    __syncthreads();

    const int per = (E + SCAT_BLOCKS - 1) / SCAT_BLOCKS;
    const int c0 = blockIdx.x * per;
    const int cend = (c0 + per < E) ? c0 + per : E;

    for (int i = c0 + t; i < cend; i += 256)
        atomicAdd(&lh[rows[i] >> 6], 1);
    __syncthreads();
    for (int b = t; b < nb; b += 256) {
        int c = lh[b];
        lbase[b] = c ? atomicAdd(&cur[b], c) : 0;
        lh[b] = 0;
    }
    __syncthreads();
    for (int i = c0 + t; i < cend; i += 256) {
        int r = rows[i];
        int b = r >> 6;
        int p = atomicAdd(&lh[b], 1);
        uint lo = ((uint)cols[i] << 8) | (uint)(r & 63);
        tcw[lbase[b] + p] = make_int2((int)lo, __float_as_int(w[i]));
    }
}

__global__ __launch_bounds__(256) void bsort_kernel(
    const int* __restrict__ bbase,
    const int2* __restrict__ t1, const int2* __restrict__ t2,
    int* __restrict__ rowp1, int* __restrict__ rowp2,
    int2* __restrict__ cw1, int2* __restrict__ cw2, int nb, int n)
{
    __shared__ int cnt[64], soff[64], pos[64];
    const int br = blockIdx.y;
    const int* bb = bbase + (size_t)br * (nb + 1);
    const int2* tcw = br ? t2 : t1;
    int* rowp = br ? rowp2 : rowp1;
    int2* cw = br ? cw2 : cw1;
    const int b = blockIdx.x;
    const int t = threadIdx.x;
    const int base = bb[b];
    const int m = bb[b + 1] - base;
    if (t < 64) cnt[t] = 0;
    __syncthreads();
    for (int i = t; i < m; i += 256) atomicAdd(&cnt[(uint)tcw[base + i].x & 63], 1);
    __syncthreads();
    if (t == 0) {
        int run = 0;
#pragma unroll
        for (int r = 0; r < 64; ++r) { soff[r] = run; run += cnt[r]; }
    }
    __syncthreads();
    if (t < 64) {
        pos[t] = soff[t];
        int g = b * 64 + t;
        if (g < n) rowp[g] = base + soff[t];
    }
    __syncthreads();
    for (int i = t; i < m; i += 256) {
        int2 e = tcw[base + i];
        int r = (uint)e.x & 63;
        int p = atomicAdd(&pos[r], 1);
        cw[base + p] = make_int2((int)((uint)e.x & 0xFFFFFF00u), e.y);  // col*256 byte offset
    }
}

// ---------------- SpMM: 4 rows/wave, 16 gathers in flight, readlane metadata ----------------
struct BrArgs {
    const int* rowp;
    const int2* cw;
    const uint* hin;
    uint* hout;
    const float* Wo;
};

// 4 edges of one row: readlane metadata (zeros beyond count are harmless), 4 gathers, 8 fma
#define EDGE4(my, acc, jj)                                                      \
    {                                                                           \
        const uint b0 = (uint)__builtin_amdgcn_readlane((my).x, (jj));          \
        const float q0 = __int_as_float(__builtin_amdgcn_readlane((my).y, (jj)));\
        const uint b1 = (uint)__builtin_amdgcn_readlane((my).x, (jj) + 1);      \
        const float q1 = __int_as_float(__builtin_amdgcn_readlane((my).y, (jj) + 1));\
        const uint b2 = (uint)__builtin_amdgcn_readlane((my).x, (jj) + 2);      \
        const float q2 = __int_as_float(__builtin_amdgcn_readlane((my).y, (jj) + 2));\
        const uint b3 = (uint)__builtin_amdgcn_readlane((my).x, (jj) + 3);      \
        const float q3 = __int_as_float(__builtin_amdgcn_readlane((my).y, (jj) + 3));\
        const uint g0 = *(const uint*)(hbase + (size_t)b0 + laneB);             \
        const uint g1 = *(const uint*)(hbase + (size_t)b1 + laneB);             \
        const uint g2 = *(const uint*)(hbase + (size_t)b2 + laneB);             \
        const uint g3 = *(const uint*)(hbase + (size_t)b3 + laneB);             \
        (acc).x = fmaf(q0, bflo(g0), (acc).x); (acc).y = fmaf(q0, bfhi(g0), (acc).y);\
        (acc).x = fmaf(q1, bflo(g1), (acc).x); (acc).y = fmaf(q1, bfhi(g1), (acc).y);\
        (acc).x = fmaf(q2, bflo(g2), (acc).x); (acc).y = fmaf(q2, bfhi(g2), (acc).y);\
        (acc).x = fmaf(q3, bflo(g3), (acc).x); (acc).y = fmaf(q3, bfhi(g3), (acc).y);\
    }

__global__ __launch_bounds__(256) void spmm2_kernel(
    BrArgs A, BrArgs B, const float* __restrict__ fW, int k,
    float* __restrict__ z2, int storeH, int n)
{
    const int bid = blockIdx.x;
    const int br = bid & 1;
    const int wv = threadIdx.x >> 6;
    const int r0 = (bid >> 1) * 16 + wv * 4;
    if (r0 >= n) return;
    const int r1 = r0 + 1, r2 = r0 + 2, r3 = r0 + 3;
    const bool v1 = r1 < n, v2 = r2 < n, v3 = r3 < n;
    const int*   rowp = br ? B.rowp : A.rowp;
    const int2*  cwp  = br ? B.cw   : A.cw;
    const uint*  hin  = br ? B.hin  : A.hin;
    uint*        hout = br ? B.hout : A.hout;
    const float* Wo   = br ? B.Wo   : A.Wo;
    const int lane = threadIdx.x & 63;
    const uint laneB = (uint)lane * 4u;
    const char* hbase = (const char*)hin;

    float w0[COUT], w1[COUT];
    const float* wp = Wo + (size_t)(lane * 2) * COUT;
#pragma unroll
    for (int c = 0; c < COUT; ++c) { w0[c] = wp[c]; w1[c] = wp[COUT + c]; }

    int sA = rowp[r0], eA = rowp[r0 + 1];
    int sB = v1 ? rowp[r1] : 0, eB = v1 ? rowp[r1 + 1] : 0;
    int sC = v2 ? rowp[r2] : 0, eC = v2 ? rowp[r2 + 1] : 0;
    int sD = v3 ? rowp[r3] : 0, eD = v3 ? rowp[r3 + 1] : 0;
    sA = __builtin_amdgcn_readfirstlane(sA); eA = __builtin_amdgcn_readfirstlane(eA);
    sB = __builtin_amdgcn_readfirstlane(sB); eB = __builtin_amdgcn_readfirstlane(eB);
    sC = __builtin_amdgcn_readfirstlane(sC); eC = __builtin_amdgcn_readfirstlane(eC);
    sD = __builtin_amdgcn_readfirstlane(sD); eD = __builtin_amdgcn_readfirstlane(eD);

    float2 accA = make_float2(0.f, 0.f), accB = make_float2(0.f, 0.f);
    float2 accC = make_float2(0.f, 0.f), accD = make_float2(0.f, 0.f);
    int iA = sA, iB = sB, iC = sC, iD = sD;

    while (iA < eA || iB < eB || iC < eC || iD < eD) {
        int cA = eA - iA; cA = cA < 0 ? 0 : (cA > 64 ? 64 : cA);
        int cB = eB - iB; cB = cB < 0 ? 0 : (cB > 64 ? 64 : cB);
        int cC = eC - iC; cC = cC < 0 ? 0 : (cC > 64 ? 64 : cC);
        int cD = eD - iD; cD = cD < 0 ? 0 : (cD > 64 ? 64 : cD);
        // load all 4 rows' metadata up-front (4 loads in flight; zeros beyond count)
        int2 myA = make_int2(0, 0), myB = make_int2(0, 0);
        int2 myC = make_int2(0, 0), myD = make_int2(0, 0);
        if (lane < cA) myA = cwp[iA + lane];
        if (lane < cB) myB = cwp[iB + lane];
        if (lane < cC) myC = cwp[iC + lane];
        if (lane < cD) myD = cwp[iD + lane];
        int m = cA < cB ? cA : cB;
        m = m < cC ? m : cC;
        m = m < cD ? m : cD;
        int j = 0;
        // joint phase: 16 gathers in flight, fully maskless
        for (; j + 3 < m; j += 4) {
            EDGE4(myA, accA, j);
            EDGE4(myB, accB, j);
            EDGE4(myC, accC, j);
            EDGE4(myD, accD, j);
        }
        // per-row remainders: maskless 4-step; readlane beyond count yields 0 -> no-op fma
        for (int jA = j; jA < cA; jA += 4) EDGE4(myA, accA, jA);
        for (int jB = j; jB < cB; jB += 4) EDGE4(myB, accB, jB);
        for (int jC = j; jC < cC; jC += 4) EDGE4(myC, accC, jC);
        for (int jD = j; jD < cD; jD += 4) EDGE4(myD, accD, jD);
        iA += cA; iB += cB; iC += cC; iD += cD;
    }

    if (storeH) {
        hout[(size_t)r0 * 64 + lane] = packbf(accA.x, accA.y);
        if (v1) hout[(size_t)r1 * 64 + lane] = packbf(accB.x, accB.y);
        if (v2) hout[(size_t)r2 * 64 + lane] = packbf(accC.x, accC.y);
        if (v3) hout[(size_t)r3 * 64 + lane] = packbf(accD.x, accD.y);
    }

    const float fw = fW[br * (KHOPS + 1) + k + 1];
    float zA = 0.f, zB = 0.f, zC = 0.f, zD = 0.f;
#pragma unroll
    for (int c = 0; c < COUT; ++c) {
        float pA = fmaf(accA.x, w0[c], accA.y * w1[c]);
        float pB = fmaf(accB.x, w0[c], accB.y * w1[c]);
        float pC = fmaf(accC.x, w0[c], accC.y * w1[c]);
        float pD = fmaf(accD.x, w0[c], accD.y * w1[c]);
#pragma unroll
        for (int off = 32; off; off >>= 1) {
            pA += __shfl_xor(pA, off); pB += __shfl_xor(pB, off);
            pC += __shfl_xor(pC, off); pD += __shfl_xor(pD, off);
        }
        if (lane == c) { zA = pA; zB = pB; zC = pC; zD = pD; }
    }
    if (lane < COUT) {
        z2[(size_t)r0 * (2 * COUT) + br * COUT + lane] += fw * zA;
        if (v1) z2[(size_t)r1 * (2 * COUT) + br * COUT + lane] += fw * zB;
        if (v2) z2[(size_t)r2 * (2 * COUT) + br * COUT + lane] += fw * zC;
        if (v3) z2[(size_t)r3 * (2 * COUT) + br * COUT + lane] += fw * zD;
    }
}

// ---------------- z2 init: fw0 * (h0 @ Wout) per branch ----------------
__global__ __launch_bounds__(256) void zacc2_kernel(
    const uint* __restrict__ h1, const uint* __restrict__ h2,
    const float* __restrict__ Wout, const float* __restrict__ fW,
    float* __restrict__ z2, int n)
{
    const int wid = (blockIdx.x * blockDim.x + threadIdx.x) >> 6;
    if (wid >= n) return;
    const int lane = threadIdx.x & 63;
    const uint u1 = h1[(size_t)wid * 64 + lane];
    const uint u2 = h2[(size_t)wid * 64 + lane];
    const float a1 = bflo(u1), b1v = bfhi(u1);
    const float a2 = bflo(u2), b2v = bfhi(u2);
    const float* wp1 = Wout + (size_t)(lane * 2) * COUT;
    const float* wp2 = Wout + (size_t)HID * COUT + (size_t)(lane * 2) * COUT;
    float zv1 = 0.f, zv2 = 0.f;
#pragma unroll
    for (int c = 0; c < COUT; ++c) {
        float p1 = fmaf(a1, wp1[c], b1v * wp1[COUT + c]);
        float p2 = fmaf(a2, wp2[c], b2v * wp2[COUT + c]);
#pragma unroll
        for (int off = 32; off; off >>= 1) { p1 += __shfl_xor(p1, off); p2 += __shfl_xor(p2, off); }
        if (lane == c) { zv1 = p1; zv2 = p2; }
    }
    if (lane < COUT) {
        z2[(size_t)wid * (2 * COUT) + lane]        = fW[0] * zv1;
        z2[(size_t)wid * (2 * COUT) + COUT + lane] = fW[KHOPS + 1] * zv2;
    }
}

// ---------------- log_softmax(z2_br0 + z2_br1 + bias) ----------------
__global__ void logsm_kernel(const float* __restrict__ z2, const float* __restrict__ bout,
                             float* __restrict__ out, int n)
{
    const int r = blockIdx.x * blockDim.x + threadIdx.x;
    if (r >= n) return;
    float v[COUT];
    float m = -1e30f;
#pragma unroll
    for (int c = 0; c < COUT; ++c) {
        v[c] = z2[(size_t)r * (2 * COUT) + c] + z2[(size_t)r * (2 * COUT) + COUT + c] + bout[c];
        m = fmaxf(m, v[c]);
    }
    float s = 0.f;
#pragma unroll
    for (int c = 0; c < COUT; ++c) s += expf(v[c] - m);
    const float l = logf(s) + m;
#pragma unroll
    for (int c = 0; c < COUT; ++c) out[(size_t)r * COUT + c] = v[c] - l;
}

extern "C" void kernel_launch(void* const* d_in, const int* in_sizes, int n_in,
                              void* d_out, int out_size, void* d_ws, size_t ws_size,
                              hipStream_t stream)
{
    const float* x    = (const float*)d_in[0];
    const int*   ei1  = (const int*)d_in[1];
    const float* ew1  = (const float*)d_in[2];
    const int*   ei2  = (const int*)d_in[3];
    const float* ew2  = (const float*)d_in[4];
    const float* Win  = (const float*)d_in[5];
    const float* bin  = (const float*)d_in[6];
    const float* fW   = (const float*)d_in[7];
    const float* Wout = (const float*)d_in[8];
    const float* bout = (const float*)d_in[9];
    const int n  = in_sizes[0] / F_IN;
    const int E1 = in_sizes[2];
    const int E2 = in_sizes[4];
    const int Emax = E1 > E2 ? E1 : E2;
    const int nb = (n + 63) / 64;
    float* zout = (float*)d_out;

    char* p = (char*)d_ws;
    auto alloc = [&](size_t bytes) { char* r = p; p += (bytes + 255) & ~(size_t)255; return r; };
    char* regA = alloc((size_t)4 * n * 64 * 4);
    uint* h1A = (uint*)regA;
    uint* h1B = (uint*)(regA + (size_t)n * 64 * 4);
    uint* h2A = (uint*)(regA + (size_t)2 * n * 64 * 4);
    uint* h2B = (uint*)(regA + (size_t)3 * n * 64 * 4);
    int2* tcw1 = (int2*)regA;
    int2* tcw2 = (int2*)(regA + (size_t)Emax * 8);
    int2* cw1  = (int2*)alloc((size_t)Emax * 8 + 256);
    int2* cw2  = (int2*)alloc((size_t)Emax * 8 + 256);
    int*  rowp1 = (int*)alloc((size_t)(n + 1) * 4);
    int*  rowp2 = (int*)alloc((size_t)(n + 1) * 4);
    float* z2  = (float*)alloc((size_t)n * 2 * COUT * 4);
    int*  bcnt  = (int*)alloc((size_t)2 * nb * 4);
    int*  bbase = (int*)alloc((size_t)2 * (nb + 1) * 4);
    int*  bcur  = (int*)alloc((size_t)2 * nb * 4);
    ushort* Wsw = (ushort*)alloc((size_t)2 * 16 * 8 * 64 * 8 * 2);

    const int rowBlocks = (n + 3) / 4;

    hipLaunchKernelGGL(wprep_kernel, dim3(64), dim3(256), 0, stream, Win, Wsw);

    hipMemsetAsync(bcnt, 0, (size_t)2 * nb * 4, stream);
    hipLaunchKernelGGL(bhist_kernel, dim3(256, 2), dim3(256), nb * 4, stream,
                       ei1, E1, ei2, E2, bcnt, nb);
    hipLaunchKernelGGL(bscan_kernel, dim3(1, 2), dim3(256), 0, stream,
                       bcnt, bbase, bcur, rowp1, rowp2, nb, n, E1, E2);
    hipLaunchKernelGGL(bscat_kernel, dim3(SCAT_BLOCKS, 2), dim3(256), 2 * nb * 4, stream,
                       ei1, ei1 + E1, ew1, E1, ei2, ei2 + E2, ew2, E2,
                       bcur, tcw1, tcw2, nb);
    hipLaunchKernelGGL(bsort_kernel, dim3(nb, 2), dim3(256), 0, stream,
                       bbase, tcw1, tcw2, rowp1, rowp2, cw1, cw2, nb, n);

    hipLaunchKernelGGL(gemm_mfma_kernel, dim3((n + 127) / 128, 2), dim3(256), 0, stream,
                       x, Wsw, bin, h1A, h2A, n);

    hipLaunchKernelGGL(zacc2_kernel, dim3(rowBlocks), dim3(256), 0, stream,
                       h1A, h2A, Wout, fW, z2, n);

    uint* cur1 = h1A; uint* nxt1 = h1B;
    uint* cur2 = h2A; uint* nxt2 = h2B;
    const int spmmBlocks = ((n + 15) / 16) * 2;
    for (int k = 0; k < KHOPS; ++k) {
        const int storeH = (k < KHOPS - 1) ? 1 : 0;
        BrArgs A { rowp1, cw1, cur1, nxt1, Wout };
        BrArgs B { rowp2, cw2, cur2, nxt2, Wout + (size_t)HID * COUT };
        hipLaunchKernelGGL(spmm2_kernel, dim3(spmmBlocks), dim3(256), 0, stream,
                           A, B, fW, k, z2, storeH, n);
        uint* t1 = cur1; cur1 = nxt1; nxt1 = t1;
        uint* t2 = cur2; cur2 = nxt2; nxt2 = t2;
    }

    hipLaunchKernelGGL(logsm_kernel, dim3((n + 255) / 256), dim3(256), 0, stream,
                       z2, bout, zout, n);
}

// Round 13
// 2586.105 us; speedup vs baseline: 1.6721x; 1.0949x over previous
//
#include <hip/hip_runtime.h>

#define F_IN 512
#define HID 128
#define KHOPS 10
#define COUT 10

typedef unsigned int uint;
typedef unsigned short ushort;
typedef float f32x4 __attribute__((ext_vector_type(4)));
typedef short bf16x8 __attribute__((ext_vector_type(8)));

__device__ __forceinline__ uint f2bf1(float f) {
    uint u = __float_as_uint(f);
    return (u + 0x7fffu + ((u >> 16) & 1u)) >> 16;   // RNE
}
__device__ __forceinline__ uint packbf(float a, float b) {
    return f2bf1(a) | (f2bf1(b) << 16);
}
__device__ __forceinline__ float bflo(uint u) { return __uint_as_float(u << 16); }
__device__ __forceinline__ float bfhi(uint u) { return __uint_as_float(u & 0xffff0000u); }

// ---------------- W_in -> bf16, pre-swizzled into MFMA B-fragment lane order ----------------
__global__ __launch_bounds__(256) void wprep_kernel(
    const float* __restrict__ Win, ushort* __restrict__ Wsw)
{
    const int t = blockIdx.x * blockDim.x + threadIdx.x;
    if (t >= 2 * 16 * 8 * 64) return;
    const int l = t & 63;
    const int c = (t >> 6) & 7;
    const int s = (t >> 9) & 15;
    const int br = t >> 13;
    const int col = c * 16 + (l & 15);
    const int k0 = s * 32 + (l >> 4) * 8;
    const float* W = Win + (size_t)br * F_IN * HID;
    uint o0 = packbf(W[(size_t)(k0 + 0) * HID + col], W[(size_t)(k0 + 1) * HID + col]);
    uint o1 = packbf(W[(size_t)(k0 + 2) * HID + col], W[(size_t)(k0 + 3) * HID + col]);
    uint o2 = packbf(W[(size_t)(k0 + 4) * HID + col], W[(size_t)(k0 + 5) * HID + col]);
    uint o3 = packbf(W[(size_t)(k0 + 6) * HID + col], W[(size_t)(k0 + 7) * HID + col]);
    *(uint4*)(Wsw + (size_t)t * 8) = make_uint4(o0, o1, o2, o3);
}

// ---------------- GEMM via MFMA: h = bf16(x @ W + b) ----------------
__global__ __launch_bounds__(256) void gemm_mfma_kernel(
    const float* __restrict__ x, const ushort* __restrict__ Wsw,
    const float* __restrict__ bin, uint* __restrict__ h1, uint* __restrict__ h2, int n)
{
    const int br = blockIdx.y;
    const uint4* Wb = (const uint4*)(Wsw + (size_t)br * 16 * 8 * 64 * 8);
    const float* bias = bin + br * HID;
    uint* h = br ? h2 : h1;

    const int w = threadIdx.x >> 6;
    const int lane = threadIdx.x & 63;
    const int r16 = lane & 15;
    const int kg = lane >> 4;

    const int rowbase = blockIdx.x * 128 + w * 32;

    f32x4 acc[2][8];
#pragma unroll
    for (int f = 0; f < 2; ++f)
#pragma unroll
        for (int c = 0; c < 8; ++c) acc[f][c] = (f32x4)0.f;

    int rA0 = rowbase + r16;      if (rA0 > n - 1) rA0 = n - 1;
    int rA1 = rowbase + 16 + r16; if (rA1 > n - 1) rA1 = n - 1;
    const float* xp0 = x + (size_t)rA0 * F_IN + kg * 8;
    const float* xp1 = x + (size_t)rA1 * F_IN + kg * 8;

    for (int s = 0; s < 16; ++s) {
        const float4 a0lo = *(const float4*)(xp0 + s * 32);
        const float4 a0hi = *(const float4*)(xp0 + s * 32 + 4);
        const float4 a1lo = *(const float4*)(xp1 + s * 32);
        const float4 a1hi = *(const float4*)(xp1 + s * 32 + 4);
        union { uint4 u; bf16x8 v; } af0, af1;
        af0.u = make_uint4(packbf(a0lo.x, a0lo.y), packbf(a0lo.z, a0lo.w),
                           packbf(a0hi.x, a0hi.y), packbf(a0hi.z, a0hi.w));
        af1.u = make_uint4(packbf(a1lo.x, a1lo.y), packbf(a1lo.z, a1lo.w),
                           packbf(a1hi.x, a1hi.y), packbf(a1hi.z, a1hi.w));
        const uint4* wq = Wb + (size_t)(s * 8) * 64 + lane;
#pragma unroll
        for (int c = 0; c < 8; ++c) {
            union { uint4 u; bf16x8 v; } bfr;
            bfr.u = wq[c * 64];
            acc[0][c] = __builtin_amdgcn_mfma_f32_16x16x32_bf16(af0.v, bfr.v, acc[0][c], 0, 0, 0);
            acc[1][c] = __builtin_amdgcn_mfma_f32_16x16x32_bf16(af1.v, bfr.v, acc[1][c], 0, 0, 0);
        }
    }

    float bv[8];
#pragma unroll
    for (int c = 0; c < 8; ++c) bv[c] = bias[c * 16 + r16];

#pragma unroll
    for (int f = 0; f < 2; ++f)
#pragma unroll
        for (int c = 0; c < 8; ++c)
#pragma unroll
            for (int i = 0; i < 4; ++i) {
                const float v = acc[f][c][i] + bv[c];
                const float o = __shfl_xor(v, 1);
                const int row = rowbase + f * 16 + kg * 4 + i;
                if (!(lane & 1) && row < n)
                    h[(size_t)row * 64 + c * 8 + (r16 >> 1)] = packbf(v, o);
            }
}

// ---------------- CSR build ----------------
// temp record: lo = (col << 8) | rowlocal, hi = w bits
// final cw record: lo = col*256 byte offset, hi = w bits
// bsort orders each row's edges by ascending col-bucket (col>>12) -> L2-window sweep

__global__ void bhist_kernel(const int* __restrict__ r1, int E1,
                             const int* __restrict__ r2, int E2,
                             int* __restrict__ bcnt, int nb)
{
    extern __shared__ int sh[];
    const int br = blockIdx.y;
    const int* rows = br ? r2 : r1;
    const int E = br ? E2 : E1;
    int* bc = bcnt + (size_t)br * nb;
    for (int i = threadIdx.x; i < nb; i += blockDim.x) sh[i] = 0;
    __syncthreads();
    for (int i = blockIdx.x * blockDim.x + threadIdx.x; i < E; i += gridDim.x * blockDim.x)
        atomicAdd(&sh[rows[i] >> 6], 1);
    __syncthreads();
    for (int i = threadIdx.x; i < nb; i += blockDim.x)
        if (sh[i]) atomicAdd(&bc[i], sh[i]);
}

__global__ __launch_bounds__(256) void bscan_kernel(
    const int* __restrict__ bcnt, int* __restrict__ bbase, int* __restrict__ bcur,
    int* __restrict__ rowp1, int* __restrict__ rowp2,
    int nb, int n, int E1, int E2)
{
    __shared__ int ssum[256];
    const int br = blockIdx.y;
    const int* bc = bcnt + (size_t)br * nb;
    int* bb = bbase + (size_t)br * (nb + 1);
    int* cur = bcur + (size_t)br * nb;
    int* rowp = br ? rowp2 : rowp1;
    const int E = br ? E2 : E1;
    const int t = threadIdx.x;
    const int chunk = (nb + 255) / 256;
    const int start = t * chunk;
    const int end = (start + chunk < nb) ? start + chunk : nb;
    int sum = 0;
    for (int i = start; i < end; ++i) sum += bc[i];
    ssum[t] = sum;
    __syncthreads();
    if (t == 0) {
        int run = 0;
        for (int i = 0; i < 256; ++i) { int v = ssum[i]; ssum[i] = run; run += v; }
        bb[nb] = E;
        rowp[n] = E;
    }
    __syncthreads();
    int run = ssum[t];
    for (int i = start; i < end; ++i) {
        bb[i] = run; cur[i] = run; run += bc[i];
    }
}

#define SCAT_BLOCKS 256
__global__ __launch_bounds__(256) void bscat_kernel(
    const int* __restrict__ r1, const int* __restrict__ c1, const float* __restrict__ w1, int E1,
    const int* __restrict__ r2, const int* __restrict__ c2, const float* __restrict__ w2, int E2,
    int* __restrict__ bcur, int2* __restrict__ t1, int2* __restrict__ t2, int nb)
{
    extern __shared__ int sh[];
    int* lh = sh;
    int* lbase = sh + nb;
    const int br = blockIdx.y;
    const int* rows = br ? r2 : r1;
    const int* cols = br ? c2 : c1;
    const float* w  = br ? w2 : w1;
    const int E = br ? E2 : E1;
    int* cur = bcur + (size_t)br * nb;
    int2* tcw = br ? t2 : t1;
    const int t = threadIdx.x;

    for (int i = t; i < nb; i += 256) lh[i] = 0;
    __syncthreads();

    const int per = (E + SCAT_BLOCKS - 1) / SCAT_BLOCKS;
    const int c0 = blockIdx.x * per;
    const int cend = (c0 + per < E) ? c0 + per : E;

    for (int i = c0 + t; i < cend; i += 256)
        atomicAdd(&lh[rows[i] >> 6], 1);
    __syncthreads();
    for (int b = t; b < nb; b += 256) {
        int c = lh[b];
        lbase[b] = c ? atomicAdd(&cur[b], c) : 0;
        lh[b] = 0;
    }
    __syncthreads();
    for (int i = c0 + t; i < cend; i += 256) {
        int r = rows[i];
        int b = r >> 6;
        int p = atomicAdd(&lh[b], 1);
        uint lo = ((uint)cols[i] << 8) | (uint)(r & 63);
        tcw[lbase[b] + p] = make_int2((int)lo, __float_as_int(w[i]));
    }
}

// counting sort per bucket by key = (rowlocal<<5) | (col>>12):
// rows contiguous; within a row edges in ascending 4096-col windows (1MB of h)
__global__ __launch_bounds__(256) void bsort_kernel(
    const int* __restrict__ bbase,
    const int2* __restrict__ t1, const int2* __restrict__ t2,
    int* __restrict__ rowp1, int* __restrict__ rowp2,
    int2* __restrict__ cw1, int2* __restrict__ cw2, int nb, int n)
{
    __shared__ int cnt[2048];
    __shared__ int pos[2048];
    __shared__ int ssum[256];
    const int br = blockIdx.y;
    const int* bb = bbase + (size_t)br * (nb + 1);
    const int2* tcw = br ? t2 : t1;
    int* rowp = br ? rowp2 : rowp1;
    int2* cw = br ? cw2 : cw1;
    const int b = blockIdx.x;
    const int t = threadIdx.x;
    const int base = bb[b];
    const int m = bb[b + 1] - base;

#pragma unroll
    for (int j = 0; j < 8; ++j) cnt[t * 8 + j] = 0;
    __syncthreads();
    for (int i = t; i < m; i += 256) {
        const uint lo = (uint)tcw[base + i].x;
        const int key = (int)(((lo & 63u) << 5) | (lo >> 20));   // rowlocal*32 + col>>12
        atomicAdd(&cnt[key], 1);
    }
    __syncthreads();
    int s = 0;
#pragma unroll
    for (int j = 0; j < 8; ++j) s += cnt[t * 8 + j];
    ssum[t] = s;
    __syncthreads();
    if (t == 0) {
        int run = 0;
        for (int i = 0; i < 256; ++i) { int v = ssum[i]; ssum[i] = run; run += v; }
    }
    __syncthreads();
    int run = ssum[t];
#pragma unroll
    for (int j = 0; j < 8; ++j) { pos[t * 8 + j] = run; run += cnt[t * 8 + j]; }
    __syncthreads();
    if (t < 64) {
        const int g = b * 64 + t;
        if (g < n) rowp[g] = base + pos[t * 32];
    }
    __syncthreads();
    for (int i = t; i < m; i += 256) {
        const int2 e = tcw[base + i];
        const uint lo = (uint)e.x;
        const int key = (int)(((lo & 63u) << 5) | (lo >> 20));
        const int p = atomicAdd(&pos[key], 1);
        cw[base + p] = make_int2((int)(lo & 0xFFFFFF00u), e.y);   // col*256 byte offset
    }
}

// ---------------- SpMM: 2 rows/wave, 8 gathers in flight, readlane metadata (R9) ----------------
struct BrArgs {
    const int* rowp;
    const int2* cw;
    const uint* hin;
    uint* hout;
    const float* Wo;
};

__global__ __launch_bounds__(256) void spmm2_kernel(
    BrArgs A, BrArgs B, const float* __restrict__ fW, int k,
    float* __restrict__ z2, int storeH, int n)
{
    const int bid = blockIdx.x;
    const int br = bid & 1;
    const int wv = threadIdx.x >> 6;
    const int r0 = (bid >> 1) * 8 + wv * 2;
    if (r0 >= n) return;
    const int r1 = r0 + 1;
    const bool has1 = (r1 < n);
    const int*   rowp = br ? B.rowp : A.rowp;
    const int2*  cwp  = br ? B.cw   : A.cw;
    const uint*  hin  = br ? B.hin  : A.hin;
    uint*        hout = br ? B.hout : A.hout;
    const float* Wo   = br ? B.Wo   : A.Wo;
    const int lane = threadIdx.x & 63;
    const uint laneB = (uint)lane * 4u;
    const char* hbase = (const char*)hin;

    float w0[COUT], w1[COUT];
    const float* wp = Wo + (size_t)(lane * 2) * COUT;
#pragma unroll
    for (int c = 0; c < COUT; ++c) { w0[c] = wp[c]; w1[c] = wp[COUT + c]; }

    int sA = rowp[r0], eA = rowp[r0 + 1];
    int sB = has1 ? rowp[r1] : 0, eB = has1 ? rowp[r1 + 1] : 0;
    sA = __builtin_amdgcn_readfirstlane(sA);
    eA = __builtin_amdgcn_readfirstlane(eA);
    sB = __builtin_amdgcn_readfirstlane(sB);
    eB = __builtin_amdgcn_readfirstlane(eB);

    float2 accA = make_float2(0.f, 0.f);
    float2 accB = make_float2(0.f, 0.f);
    int iA = sA, iB = sB;

    while (iA < eA || iB < eB) {
        int cA = eA - iA; cA = cA > 64 ? 64 : (cA < 0 ? 0 : cA);
        int cB = eB - iB; cB = cB > 64 ? 64 : (cB < 0 ? 0 : cB);
        int2 myA = make_int2(0, 0), myB = make_int2(0, 0);
        if (lane < cA) myA = cwp[iA + lane];
        if (lane < cB) myB = cwp[iB + lane];
        const int m = cA > cB ? cA : cB;
        int j = 0;
        for (; j + 3 < m; j += 4) {
            uint boA[4], boB[4];
            float qA[4], qB[4];
#pragma unroll
            for (int t2 = 0; t2 < 4; ++t2) {
                const int jt = j + t2;
                const uint ax = (uint)__builtin_amdgcn_readlane(myA.x, jt);
                const int  ay = __builtin_amdgcn_readlane(myA.y, jt);
                const uint bx = (uint)__builtin_amdgcn_readlane(myB.x, jt);
                const int  by = __builtin_amdgcn_readlane(myB.y, jt);
                const bool okA = jt < cA, okB = jt < cB;
                boA[t2] = okA ? ax : 0u;  qA[t2] = okA ? __int_as_float(ay) : 0.f;
                boB[t2] = okB ? bx : 0u;  qB[t2] = okB ? __int_as_float(by) : 0.f;
            }
            const uint gA0 = *(const uint*)(hbase + (size_t)boA[0] + laneB);
            const uint gB0 = *(const uint*)(hbase + (size_t)boB[0] + laneB);
            const uint gA1 = *(const uint*)(hbase + (size_t)boA[1] + laneB);
            const uint gB1 = *(const uint*)(hbase + (size_t)boB[1] + laneB);
            const uint gA2 = *(const uint*)(hbase + (size_t)boA[2] + laneB);
            const uint gB2 = *(const uint*)(hbase + (size_t)boB[2] + laneB);
            const uint gA3 = *(const uint*)(hbase + (size_t)boA[3] + laneB);
            const uint gB3 = *(const uint*)(hbase + (size_t)boB[3] + laneB);
            accA.x = fmaf(qA[0], bflo(gA0), accA.x); accA.y = fmaf(qA[0], bfhi(gA0), accA.y);
            accB.x = fmaf(qB[0], bflo(gB0), accB.x); accB.y = fmaf(qB[0], bfhi(gB0), accB.y);
            accA.x = fmaf(qA[1], bflo(gA1), accA.x); accA.y = fmaf(qA[1], bfhi(gA1), accA.y);
            accB.x = fmaf(qB[1], bflo(gB1), accB.x); accB.y = fmaf(qB[1], bfhi(gB1), accB.y);
            accA.x = fmaf(qA[2], bflo(gA2), accA.x); accA.y = fmaf(qA[2], bfhi(gA2), accA.y);
            accB.x = fmaf(qB[2], bflo(gB2), accB.x); accB.y = fmaf(qB[2], bfhi(gB2), accB.y);
            accA.x = fmaf(qA[3], bflo(gA3), accA.x); accA.y = fmaf(qA[3], bfhi(gA3), accA.y);
            accB.x = fmaf(qB[3], bflo(gB3), accB.x); accB.y = fmaf(qB[3], bfhi(gB3), accB.y);
        }
        for (; j < m; ++j) {
            const uint ax = (uint)__builtin_amdgcn_readlane(myA.x, j);
            const int  ay = __builtin_amdgcn_readlane(myA.y, j);
            const uint bx = (uint)__builtin_amdgcn_readlane(myB.x, j);
            const int  by = __builtin_amdgcn_readlane(myB.y, j);
            const bool okA = j < cA, okB = j < cB;
            const uint boA = okA ? ax : 0u;  const float qA = okA ? __int_as_float(ay) : 0.f;
            const uint boB = okB ? bx : 0u;  const float qB = okB ? __int_as_float(by) : 0.f;
            const uint gA = *(const uint*)(hbase + (size_t)boA + laneB);
            const uint gB = *(const uint*)(hbase + (size_t)boB + laneB);
            accA.x = fmaf(qA, bflo(gA), accA.x); accA.y = fmaf(qA, bfhi(gA), accA.y);
            accB.x = fmaf(qB, bflo(gB), accB.x); accB.y = fmaf(qB, bfhi(gB), accB.y);
        }
        iA += cA; iB += cB;
    }

    if (storeH) {
        hout[(size_t)r0 * 64 + lane] = packbf(accA.x, accA.y);
        if (has1) hout[(size_t)r1 * 64 + lane] = packbf(accB.x, accB.y);
    }

    const float fw = fW[br * (KHOPS + 1) + k + 1];
    float zA = 0.f, zB = 0.f;
#pragma unroll
    for (int c = 0; c < COUT; ++c) {
        float pA = fmaf(accA.x, w0[c], accA.y * w1[c]);
        float pB = fmaf(accB.x, w0[c], accB.y * w1[c]);
#pragma unroll
        for (int off = 32; off; off >>= 1) { pA += __shfl_xor(pA, off); pB += __shfl_xor(pB, off); }
        if (lane == c) { zA = pA; zB = pB; }
    }
    if (lane < COUT) {
        z2[(size_t)r0 * (2 * COUT) + br * COUT + lane] += fw * zA;
        if (has1) z2[(size_t)r1 * (2 * COUT) + br * COUT + lane] += fw * zB;
    }
}

// ---------------- z2 init: fw0 * (h0 @ Wout) per branch ----------------
__global__ __launch_bounds__(256) void zacc2_kernel(
    const uint* __restrict__ h1, const uint* __restrict__ h2,
    const float* __restrict__ Wout, const float* __restrict__ fW,
    float* __restrict__ z2, int n)
{
    const int wid = (blockIdx.x * blockDim.x + threadIdx.x) >> 6;
    if (wid >= n) return;
    const int lane = threadIdx.x & 63;
    const uint u1 = h1[(size_t)wid * 64 + lane];
    const uint u2 = h2[(size_t)wid * 64 + lane];
    const float a1 = bflo(u1), b1v = bfhi(u1);
    const float a2 = bflo(u2), b2v = bfhi(u2);
    const float* wp1 = Wout + (size_t)(lane * 2) * COUT;
    const float* wp2 = Wout + (size_t)HID * COUT + (size_t)(lane * 2) * COUT;
    float zv1 = 0.f, zv2 = 0.f;
#pragma unroll
    for (int c = 0; c < COUT; ++c) {
        float p1 = fmaf(a1, wp1[c], b1v * wp1[COUT + c]);
        float p2 = fmaf(a2, wp2[c], b2v * wp2[COUT + c]);
#pragma unroll
        for (int off = 32; off; off >>= 1) { p1 += __shfl_xor(p1, off); p2 += __shfl_xor(p2, off); }
        if (lane == c) { zv1 = p1; zv2 = p2; }
    }
    if (lane < COUT) {
        z2[(size_t)wid * (2 * COUT) + lane]        = fW[0] * zv1;
        z2[(size_t)wid * (2 * COUT) + COUT + lane] = fW[KHOPS + 1] * zv2;
    }
}

// ---------------- log_softmax(z2_br0 + z2_br1 + bias) ----------------
__global__ void logsm_kernel(const float* __restrict__ z2, const float* __restrict__ bout,
                             float* __restrict__ out, int n)
{
    const int r = blockIdx.x * blockDim.x + threadIdx.x;
    if (r >= n) return;
    float v[COUT];
    float m = -1e30f;
#pragma unroll
    for (int c = 0; c < COUT; ++c) {
        v[c] = z2[(size_t)r * (2 * COUT) + c] + z2[(size_t)r * (2 * COUT) + COUT + c] + bout[c];
        m = fmaxf(m, v[c]);
    }
    float s = 0.f;
#pragma unroll
    for (int c = 0; c < COUT; ++c) s += expf(v[c] - m);
    const float l = logf(s) + m;
#pragma unroll
    for (int c = 0; c < COUT; ++c) out[(size_t)r * COUT + c] = v[c] - l;
}

extern "C" void kernel_launch(void* const* d_in, const int* in_sizes, int n_in,
                              void* d_out, int out_size, void* d_ws, size_t ws_size,
                              hipStream_t stream)
{
    const float* x    = (const float*)d_in[0];
    const int*   ei1  = (const int*)d_in[1];
    const float* ew1  = (const float*)d_in[2];
    const int*   ei2  = (const int*)d_in[3];
    const float* ew2  = (const float*)d_in[4];
    const float* Win  = (const float*)d_in[5];
    const float* bin  = (const float*)d_in[6];
    const float* fW   = (const float*)d_in[7];
    const float* Wout = (const float*)d_in[8];
    const float* bout = (const float*)d_in[9];
    const int n  = in_sizes[0] / F_IN;
    const int E1 = in_sizes[2];
    const int E2 = in_sizes[4];
    const int Emax = E1 > E2 ? E1 : E2;
    const int nb = (n + 63) / 64;
    float* zout = (float*)d_out;

    char* p = (char*)d_ws;
    auto alloc = [&](size_t bytes) { char* r = p; p += (bytes + 255) & ~(size_t)255; return r; };
    char* regA = alloc((size_t)4 * n * 64 * 4);
    uint* h1A = (uint*)regA;
    uint* h1B = (uint*)(regA + (size_t)n * 64 * 4);
    uint* h2A = (uint*)(regA + (size_t)2 * n * 64 * 4);
    uint* h2B = (uint*)(regA + (size_t)3 * n * 64 * 4);
    int2* tcw1 = (int2*)regA;
    int2* tcw2 = (int2*)(regA + (size_t)Emax * 8);
    int2* cw1  = (int2*)alloc((size_t)Emax * 8 + 256);
    int2* cw2  = (int2*)alloc((size_t)Emax * 8 + 256);
    int*  rowp1 = (int*)alloc((size_t)(n + 1) * 4);
    int*  rowp2 = (int*)alloc((size_t)(n + 1) * 4);
    float* z2  = (float*)alloc((size_t)n * 2 * COUT * 4);
    int*  bcnt  = (int*)alloc((size_t)2 * nb * 4);
    int*  bbase = (int*)alloc((size_t)2 * (nb + 1) * 4);
    int*  bcur  = (int*)alloc((size_t)2 * nb * 4);
    ushort* Wsw = (ushort*)alloc((size_t)2 * 16 * 8 * 64 * 8 * 2);

    const int rowBlocks = (n + 3) / 4;

    hipLaunchKernelGGL(wprep_kernel, dim3(64), dim3(256), 0, stream, Win, Wsw);

    hipMemsetAsync(bcnt, 0, (size_t)2 * nb * 4, stream);
    hipLaunchKernelGGL(bhist_kernel, dim3(256, 2), dim3(256), nb * 4, stream,
                       ei1, E1, ei2, E2, bcnt, nb);
    hipLaunchKernelGGL(bscan_kernel, dim3(1, 2), dim3(256), 0, stream,
                       bcnt, bbase, bcur, rowp1, rowp2, nb, n, E1, E2);
    hipLaunchKernelGGL(bscat_kernel, dim3(SCAT_BLOCKS, 2), dim3(256), 2 * nb * 4, stream,
                       ei1, ei1 + E1, ew1, E1, ei2, ei2 + E2, ew2, E2,
                       bcur, tcw1, tcw2, nb);
    hipLaunchKernelGGL(bsort_kernel, dim3(nb, 2), dim3(256), 0, stream,
                       bbase, tcw1, tcw2, rowp1, rowp2, cw1, cw2, nb, n);

    hipLaunchKernelGGL(gemm_mfma_kernel, dim3((n + 127) / 128, 2), dim3(256), 0, stream,
                       x, Wsw, bin, h1A, h2A, n);

    hipLaunchKernelGGL(zacc2_kernel, dim3(rowBlocks), dim3(256), 0, stream,
                       h1A, h2A, Wout, fW, z2, n);

    uint* cur1 = h1A; uint* nxt1 = h1B;
    uint* cur2 = h2A; uint* nxt2 = h2B;
    const int spmmBlocks = ((n + 7) / 8) * 2;
    for (int k = 0; k < KHOPS; ++k) {
        const int storeH = (k < KHOPS - 1) ? 1 : 0;
        BrArgs A { rowp1, cw1, cur1, nxt1, Wout };
        BrArgs B { rowp2, cw2, cur2, nxt2, Wout + (size_t)HID * COUT };
        hipLaunchKernelGGL(spmm2_kernel, dim3(spmmBlocks), dim3(256), 0, stream,
                           A, B, fW, k, z2, storeH, n);
        uint* t1 = cur1; cur1 = nxt1; nxt1 = t1;
        uint* t2 = cur2; cur2 = nxt2; nxt2 = t2;
    }

    hipLaunchKernelGGL(logsm_kernel, dim3((n + 255) / 256), dim3(256), 0, stream,
                       z2, bout, zout, n);
}